// Round 8
// baseline (604.250 us; speedup 1.0000x reference)
//
#include <hip/hip_runtime.h>
#include <hip/hip_fp16.h>
#include <math.h>

__device__ __forceinline__ float lrelu(float x){ return x > 0.f ? x : 0.2f * x; }

// Per-block LDS histogram of dst-buckets -> few global atomics per block.
__global__ __launch_bounds__(256) void bhist_kernel(
    const int* __restrict__ dst, int E, int shift, int nbk, int* __restrict__ bcount)
{
  __shared__ int hist[512];
  int t = threadIdx.x;
  for (int i = t; i < nbk; i += 256) hist[i] = 0;
  __syncthreads();
  long base = (long)blockIdx.x * 4096;
  #pragma unroll
  for (int k = 0; k < 16; ++k){
    long e = base + (long)k * 256 + t;
    if (e < E) atomicAdd(&hist[dst[e] >> shift], 1);
  }
  __syncthreads();
  for (int i = t; i < nbk; i += 256){
    int v = hist[i];
    if (v) atomicAdd(&bcount[i], v);
  }
}

// Single-block exclusive scan of bucket counts -> bucket start cursors.
__global__ __launch_bounds__(512) void bscan_kernel(
    const int* __restrict__ bcount, int nbk, int* __restrict__ gcur)
{
  __shared__ int sh[512];
  int t = threadIdx.x;
  int v = (t < nbk) ? bcount[t] : 0;
  sh[t] = v; __syncthreads();
  for (int off = 1; off < 512; off <<= 1){
    int x = (t >= off) ? sh[t - off] : 0;
    __syncthreads();
    sh[t] += x;
    __syncthreads();
  }
  if (t < nbk) gcur[t] = sh[t] - v;   // exclusive bucket start
}

// Bin edges by coarse dst-bucket (packed u32: src<<shift | local_dst).
// After this kernel, gcur[b] == END offset of bucket b's edge range.
__global__ __launch_bounds__(256) void bin_kernel(
    const int* __restrict__ src, const int* __restrict__ dst, int E, int shift, int nbk,
    int* __restrict__ gcur, unsigned* __restrict__ ebuf)
{
  __shared__ int hist[512];
  __shared__ int lbase[512];
  int t = threadIdx.x;
  int mask = (1 << shift) - 1;
  long base = (long)blockIdx.x * 4096;
  for (int i = t; i < nbk; i += 256) hist[i] = 0;
  __syncthreads();
  int s_[16], d_[16];
  #pragma unroll
  for (int k = 0; k < 16; ++k){
    long e = base + (long)k * 256 + t;
    if (e < E){
      s_[k] = src[e]; d_[k] = dst[e];
      atomicAdd(&hist[d_[k] >> shift], 1);
    } else d_[k] = -1;
  }
  __syncthreads();
  for (int i = t; i < nbk; i += 256){
    lbase[i] = atomicAdd(&gcur[i], hist[i]);
    hist[i] = 0;
  }
  __syncthreads();
  #pragma unroll
  for (int k = 0; k < 16; ++k){
    if (d_[k] >= 0){
      int b = d_[k] >> shift;
      int r = atomicAdd(&hist[b], 1);
      ebuf[lbase[b] + r] = ((unsigned)s_[k] << shift) | (unsigned)(d_[k] & mask);
    }
  }
}

// One workgroup OWNS one bucket: LDS per-node degree histogram -> block-local
// exclusive scan -> coalesced (start,deg) int2 writes -> LDS-cursor CSR placement.
__global__ __launch_bounds__(512) void fill_csr4_kernel(
    const unsigned* __restrict__ ebuf, const int* __restrict__ bend,
    int shift, int N, int2* __restrict__ sd, int* __restrict__ csr_src)
{
  __shared__ int cnt[4096];               // supports shift <= 12
  __shared__ int psum[512];
  int b = blockIdx.x;
  int t = threadIdx.x;
  int bsz = 1 << shift;
  int mask = bsz - 1;
  int nbase = b << shift;
  for (int i = t; i < bsz; i += 512) cnt[i] = 0;
  __syncthreads();
  int gs = (b == 0) ? 0 : bend[b - 1];
  int ge = bend[b];
  for (int e = gs + t; e < ge; e += 512)
    atomicAdd(&cnt[ebuf[e] & mask], 1);
  __syncthreads();
  // two-level exclusive scan over cnt[0..bsz)
  int k = bsz >> 9;                       // elems per thread (>=1)
  int base = t * k;
  int loc = 0;
  for (int j = 0; j < k; ++j) loc += cnt[base + j];
  psum[t] = loc;
  __syncthreads();
  for (int off = 1; off < 512; off <<= 1){
    int x = (t >= off) ? psum[t - off] : 0;
    __syncthreads();
    psum[t] += x;
    __syncthreads();
  }
  int run = gs + psum[t] - loc;           // global exclusive prefix for chunk
  for (int j = 0; j < k; ++j){
    int node = nbase + base + j;
    int c = cnt[base + j];
    cnt[base + j] = run;                  // becomes placement cursor
    if (node < N) sd[node] = make_int2(run, c);
    run += c;
  }
  __syncthreads();
  for (int e = gs + t; e < ge; e += 512){
    unsigned v = ebuf[e];
    int slot = atomicAdd(&cnt[v & mask], 1);
    csr_src[slot] = (int)(v >> shift);
  }
}

// f = h @ W (32x32) stored as FP16 (64B/row -> 1 line per edge gather),
// el/er = per-head dot with al/ar in fp32. One thread per node.
__global__ __launch_bounds__(256) void fc_kernel(
    const float* __restrict__ hin, const int* __restrict__ nid,
    const float* __restrict__ W, const float* __restrict__ al, const float* __restrict__ ar,
    int n, __half* __restrict__ fh, float* __restrict__ el, float* __restrict__ er)
{
  __shared__ __align__(16) float Ws[1024];
  __shared__ float als[32], ars[32];
  int t = threadIdx.x;
  for (int i = t; i < 1024; i += 256) Ws[i] = W[i];
  if (t < 32){ als[t] = al[t]; ars[t] = ar[t]; }
  __syncthreads();
  int i = blockIdx.x * 256 + t;
  if (i >= n) return;
  long row = nid ? (long)nid[i] : (long)i;
  const float4* hp = (const float4*)(hin + row * 32);
  float h[32];
  #pragma unroll
  for (int q = 0; q < 8; ++q){
    float4 v = hp[q];
    h[4*q+0] = v.x; h[4*q+1] = v.y; h[4*q+2] = v.z; h[4*q+3] = v.w;
  }
  float fv[32];
  #pragma unroll
  for (int j = 0; j < 32; j += 4){
    float ax = 0.f, ay = 0.f, az = 0.f, aw = 0.f;
    #pragma unroll
    for (int k = 0; k < 32; ++k){
      float hk = h[k];
      float4 w = *(const float4*)&Ws[k*32 + j];
      ax += hk * w.x; ay += hk * w.y; az += hk * w.z; aw += hk * w.w;
    }
    fv[j] = ax; fv[j+1] = ay; fv[j+2] = az; fv[j+3] = aw;
  }
  __half hrow[32];
  #pragma unroll
  for (int j = 0; j < 32; ++j) hrow[j] = __float2half_rn(fv[j]);
  float4* fp = (float4*)(fh + (size_t)i * 32);
  #pragma unroll
  for (int q = 0; q < 4; ++q) fp[q] = ((const float4*)hrow)[q];
  float elv[4], erv[4];
  #pragma unroll
  for (int hh = 0; hh < 4; ++hh){
    float a = 0.f, b = 0.f;
    #pragma unroll
    for (int d = 0; d < 8; ++d){
      a += fv[hh*8 + d] * als[hh*8 + d];
      b += fv[hh*8 + d] * ars[hh*8 + d];
    }
    elv[hh] = a; erv[hh] = b;
  }
  *(float4*)(el + (size_t)i * 4) = make_float4(elv[0], elv[1], elv[2], elv[3]);
  *(float4*)(er + (size_t)i * 4) = make_float4(erv[0], erv[1], erv[2], erv[3]);
}

// Thread-per-node softmax: serial pass computes per-head denominators, second
// pass writes NORMALIZED alpha per edge as fp16x4 (coalesced: node edge ranges
// are contiguous). 64 nodes per wave -> no wave reductions, no idle lanes.
__global__ __launch_bounds__(256) void alpha_kernel(
    const int* __restrict__ csr_src, const int2* __restrict__ sd,
    const float* __restrict__ el, const float* __restrict__ er,
    int n, __half* __restrict__ ax)
{
  int i = blockIdx.x * 256 + threadIdx.x;
  if (i >= n) return;
  int2 sdv = sd[i];
  int s = sdv.x, d = sdv.y;
  if (d == 0) return;
  float4 er4 = *(const float4*)(er + (size_t)i * 4);
  float s0 = 0.f, s1 = 0.f, s2 = 0.f, s3 = 0.f;
  for (int e = s; e < s + d; ++e){
    int u = csr_src[e];
    float4 l4 = *(const float4*)(el + (size_t)u * 4);
    s0 += __expf(lrelu(l4.x + er4.x));
    s1 += __expf(lrelu(l4.y + er4.y));
    s2 += __expf(lrelu(l4.z + er4.z));
    s3 += __expf(lrelu(l4.w + er4.w));
  }
  float r0 = 1.f / s0, r1 = 1.f / s1, r2 = 1.f / s2, r3 = 1.f / s3;
  for (int e = s; e < s + d; ++e){
    int u = csr_src[e];
    float4 l4 = *(const float4*)(el + (size_t)u * 4);
    __half2 a01 = __halves2half2(__float2half_rn(__expf(lrelu(l4.x + er4.x)) * r0),
                                 __float2half_rn(__expf(lrelu(l4.y + er4.y)) * r1));
    __half2 a23 = __halves2half2(__float2half_rn(__expf(lrelu(l4.z + er4.z)) * r2),
                                 __float2half_rn(__expf(lrelu(l4.w + er4.w)) * r3));
    uint2 pk;
    pk.x = *(unsigned*)&a01;
    pk.y = *(unsigned*)&a23;
    *(uint2*)(ax + (size_t)e * 4) = pk;
  }
}

// Pure gather: one wave per dst node, 8 lanes per edge (fp16 col-quad), alpha
// pre-normalized. No LDS, no softmax reductions, unified path for any degree.
__global__ __launch_bounds__(256) void gat_agg_kernel(
    const int* __restrict__ csr_src, const int2* __restrict__ sd,
    const __half* __restrict__ fh, const __half* __restrict__ ax,
    const float* __restrict__ bias, int n, float* __restrict__ hout)
{
  int wid  = threadIdx.x >> 6;
  int lane = threadIdx.x & 63;
  int v = blockIdx.x * 4 + wid;
  if (v >= n) return;
  int2 sdv = sd[v];
  int s = sdv.x, d = sdv.y;
  int cq    = lane & 7;    // col-quad: cols 4cq..4cq+3
  int g     = lane >> 3;   // edge group 0..7
  int headq = cq >> 1;     // head of this col-quad

  float4 o4 = make_float4(0.f, 0.f, 0.f, 0.f);
  for (int i = g; i < d; i += 8){
    int e = s + i;
    int u = csr_src[e];                                  // 8-lane broadcast
    float a = __half2float(ax[(size_t)e * 4 + headq]);   // L1/L2 (coalesced-written)
    uint2 raw = *(const uint2*)(fh + ((size_t)u << 5) + (cq << 2));
    float2 f01 = __half22float2(*(const __half2*)&raw.x);
    float2 f23 = __half22float2(*(const __half2*)&raw.y);
    o4.x = fmaf(a, f01.x, o4.x);
    o4.y = fmaf(a, f01.y, o4.y);
    o4.z = fmaf(a, f23.x, o4.z);
    o4.w = fmaf(a, f23.y, o4.w);
  }
  #pragma unroll
  for (int off = 32; off >= 8; off >>= 1){
    o4.x += __shfl_xor(o4.x, off);
    o4.y += __shfl_xor(o4.y, off);
    o4.z += __shfl_xor(o4.z, off);
    o4.w += __shfl_xor(o4.w, off);
  }
  if (lane < 8){
    float4 b4 = *(const float4*)(bias + cq * 4);
    float4 r;
    r.x = fmaxf(o4.x + b4.x, 0.f);
    r.y = fmaxf(o4.y + b4.y, 0.f);
    r.z = fmaxf(o4.z + b4.z, 0.f);
    r.w = fmaxf(o4.w + b4.w, 0.f);
    *(float4*)(hout + (size_t)v * 32 + cq * 4) = r;
  }
}

__device__ int lower_bound_dev(const int* a, int n, int key){
  int lo = 0, hi = n;
  while (lo < hi){
    int mid = (lo + hi) >> 1;
    if (a[mid] < key) lo = mid + 1; else hi = mid;
  }
  return lo;
}

// 8 slices per graph, atomic partial sums into hg (hg pre-zeroed).
__global__ void pool_kernel(const float* __restrict__ hout, const int* __restrict__ gid,
                            int n, float* __restrict__ hg){
  __shared__ int lohi[2];
  int g  = blockIdx.x >> 3;
  int sl = blockIdx.x & 7;
  int t = threadIdx.x;
  if (t < 2) lohi[t] = lower_bound_dev(gid, n, g + t);
  __syncthreads();
  int lo = lohi[0], hi = lohi[1];
  int cnt = hi - lo;
  if (cnt <= 0) return;
  int chunk = (cnt + 7) >> 3;
  int rlo = lo + sl * chunk;
  int rhi = min(rlo + chunk, hi);
  if (rlo >= rhi) return;
  int col = t & 31, r0 = t >> 5;
  float acc = 0.f;
  for (int r = rlo + r0; r < rhi; r += 8)
    acc += hout[(size_t)r * 32 + col];
  __shared__ float red[256];
  red[t] = acc; __syncthreads();
  if (t < 128) red[t] += red[t + 128];
  __syncthreads();
  if (t < 64) red[t] += red[t + 64];
  __syncthreads();
  if (t < 32) atomicAdd(&hg[g * 32 + t], red[t] + red[t + 32]);
}

// Scorer MLP; folds the mean-pool divide (counts via binary search on gid).
__global__ void score_kernel(const float* __restrict__ hg, const int* __restrict__ gid, int n,
                             const float* __restrict__ sw1, const float* __restrict__ sb1,
                             const float* __restrict__ sw2, const float* __restrict__ sb2,
                             int B, float* __restrict__ out){
  int g = blockIdx.x * blockDim.x + threadIdx.x;
  if (g >= B) return;
  int lo = lower_bound_dev(gid, n, g);
  int hi = lower_bound_dev(gid, n, g + 1);
  float inv = 1.f / fmaxf((float)(hi - lo), 1.f);
  float hvec[32];
  const float4* hp = (const float4*)(hg + g * 32);
  #pragma unroll
  for (int q = 0; q < 8; ++q){
    float4 v = hp[q];
    hvec[4*q+0] = v.x * inv; hvec[4*q+1] = v.y * inv;
    hvec[4*q+2] = v.z * inv; hvec[4*q+3] = v.w * inv;
  }
  float o = sb2[0];
  #pragma unroll
  for (int j = 0; j < 32; ++j){
    float a = sb1[j];
    #pragma unroll
    for (int k = 0; k < 32; ++k) a += hvec[k] * sw1[k*32 + j];
    o += fmaxf(a, 0.f) * sw2[j];
  }
  out[g] = o;
}

extern "C" void kernel_launch(void* const* d_in, const int* in_sizes, int n_in,
                              void* d_out, int out_size, void* d_ws, size_t ws_size,
                              hipStream_t stream)
{
  const int*   node_ids = (const int*)d_in[0];
  const int*   srcp     = (const int*)d_in[1];
  const int*   dstp     = (const int*)d_in[2];
  const int*   gid      = (const int*)d_in[3];
  const float* emb      = (const float*)d_in[4];
  const float* W0       = (const float*)d_in[5];
  const float* al0      = (const float*)d_in[6];
  const float* ar0      = (const float*)d_in[7];
  const float* b0       = (const float*)d_in[8];
  const float* W1       = (const float*)d_in[9];
  const float* al1      = (const float*)d_in[10];
  const float* ar1      = (const float*)d_in[11];
  const float* b1       = (const float*)d_in[12];
  const float* sw1      = (const float*)d_in[13];
  const float* sb1      = (const float*)d_in[14];
  const float* sw2      = (const float*)d_in[15];
  const float* sb2      = (const float*)d_in[16];

  int N = in_sizes[0];
  int E = in_sizes[1];
  int B = out_size;           // output is [B,1] float32
  float* out = (float*)d_out;

  // Workspace carve-out (256B aligned)
  char* p = (char*)d_ws;
  auto alloc = [&](size_t bytes) -> char* {
    char* r = p;
    p += (bytes + 255) & ~(size_t)255;
    return r;
  };
  // Coarse dst-buckets: one workgroup per bucket in the fill pass.
  int shift = 9;
  while ((((long)N + (1L << shift) - 1) >> shift) > 512 && shift < 12) ++shift;
  int nbk = (int)(((long)N + (1L << shift) - 1) >> shift);

  int2*     sd      = (int2*)alloc((size_t)N * 8);
  int*      bcount  = (int*)alloc((size_t)nbk * 4);
  int*      gcur    = (int*)alloc((size_t)nbk * 4);
  int*      csr_src = (int*)alloc((size_t)E * 4);
  float*    el      = (float*)alloc((size_t)N * 16);
  float*    er      = (float*)alloc((size_t)N * 16);
  size_t fbytes  = (size_t)N * 64;          // fp16 f rows
  size_t ebytes  = (size_t)E * 4;
  __half*   fh      = (__half*)alloc(fbytes > ebytes ? fbytes : ebytes);
  __half*   ax      = (__half*)alloc((size_t)E * 8);   // fp16x4 normalized alpha per edge
  float*    h       = (float*)alloc((size_t)N * 128);
  float*    hg      = (float*)alloc((size_t)B * 32 * 4);
  unsigned* ebuf    = (unsigned*)fh;  // disjoint lifetime: consumed before fc writes fh

  hipMemsetAsync(bcount, 0, (size_t)nbk * 4, stream);
  hipMemsetAsync(hg, 0, (size_t)B * 32 * 4, stream);

  int eb4k = (E + 4095) / 4096;
  bhist_kernel<<<eb4k, 256, 0, stream>>>(dstp, E, shift, nbk, bcount);
  bscan_kernel<<<1, 512, 0, stream>>>(bcount, nbk, gcur);
  bin_kernel<<<eb4k, 256, 0, stream>>>(srcp, dstp, E, shift, nbk, gcur, ebuf);
  // after bin: gcur[b] == end offset of bucket b
  fill_csr4_kernel<<<nbk, 512, 0, stream>>>(ebuf, gcur, shift, N, sd, csr_src);

  int nblk = (N + 255) / 256;
  int ablk = (N + 3) / 4;
  // Layer 0: h_in = emb[node_ids]
  fc_kernel<<<nblk, 256, 0, stream>>>(emb, node_ids, W0, al0, ar0, N, fh, el, er);
  alpha_kernel<<<nblk, 256, 0, stream>>>(csr_src, sd, el, er, N, ax);
  gat_agg_kernel<<<ablk, 256, 0, stream>>>(csr_src, sd, fh, ax, b0, N, h);
  // Layer 1: h_in = h
  fc_kernel<<<nblk, 256, 0, stream>>>(h, nullptr, W1, al1, ar1, N, fh, el, er);
  alpha_kernel<<<nblk, 256, 0, stream>>>(csr_src, sd, el, er, N, ax);
  gat_agg_kernel<<<ablk, 256, 0, stream>>>(csr_src, sd, fh, ax, b1, N, h);

  pool_kernel<<<B * 8, 256, 0, stream>>>(h, gid, N, hg);
  score_kernel<<<1, 64, 0, stream>>>(hg, gid, N, sw1, sb1, sw2, sb2, B, out);
}

// Round 9
// 409.001 us; speedup vs baseline: 1.4774x; 1.4774x over previous
//
#include <hip/hip_runtime.h>
#include <hip/hip_fp16.h>
#include <math.h>

__device__ __forceinline__ float lrelu(float x){ return x > 0.f ? x : 0.2f * x; }

// Per-block LDS histogram of dst-buckets -> few global atomics per block.
__global__ __launch_bounds__(256) void bhist_kernel(
    const int* __restrict__ dst, int E, int shift, int nbk, int* __restrict__ bcount)
{
  __shared__ int hist[512];
  int t = threadIdx.x;
  for (int i = t; i < nbk; i += 256) hist[i] = 0;
  __syncthreads();
  long base = (long)blockIdx.x * 4096;
  #pragma unroll
  for (int k = 0; k < 16; ++k){
    long e = base + (long)k * 256 + t;
    if (e < E) atomicAdd(&hist[dst[e] >> shift], 1);
  }
  __syncthreads();
  for (int i = t; i < nbk; i += 256){
    int v = hist[i];
    if (v) atomicAdd(&bcount[i], v);
  }
}

// Single-block exclusive scan of bucket counts -> bucket start cursors.
__global__ __launch_bounds__(512) void bscan_kernel(
    const int* __restrict__ bcount, int nbk, int* __restrict__ gcur)
{
  __shared__ int sh[512];
  int t = threadIdx.x;
  int v = (t < nbk) ? bcount[t] : 0;
  sh[t] = v; __syncthreads();
  for (int off = 1; off < 512; off <<= 1){
    int x = (t >= off) ? sh[t - off] : 0;
    __syncthreads();
    sh[t] += x;
    __syncthreads();
  }
  if (t < nbk) gcur[t] = sh[t] - v;   // exclusive bucket start
}

// Bin edges by coarse dst-bucket (packed u32: src<<shift | local_dst).
// After this kernel, gcur[b] == END offset of bucket b's edge range.
__global__ __launch_bounds__(256) void bin_kernel(
    const int* __restrict__ src, const int* __restrict__ dst, int E, int shift, int nbk,
    int* __restrict__ gcur, unsigned* __restrict__ ebuf)
{
  __shared__ int hist[512];
  __shared__ int lbase[512];
  int t = threadIdx.x;
  int mask = (1 << shift) - 1;
  long base = (long)blockIdx.x * 4096;
  for (int i = t; i < nbk; i += 256) hist[i] = 0;
  __syncthreads();
  int s_[16], d_[16];
  #pragma unroll
  for (int k = 0; k < 16; ++k){
    long e = base + (long)k * 256 + t;
    if (e < E){
      s_[k] = src[e]; d_[k] = dst[e];
      atomicAdd(&hist[d_[k] >> shift], 1);
    } else d_[k] = -1;
  }
  __syncthreads();
  for (int i = t; i < nbk; i += 256){
    lbase[i] = atomicAdd(&gcur[i], hist[i]);
    hist[i] = 0;
  }
  __syncthreads();
  #pragma unroll
  for (int k = 0; k < 16; ++k){
    if (d_[k] >= 0){
      int b = d_[k] >> shift;
      int r = atomicAdd(&hist[b], 1);
      ebuf[lbase[b] + r] = ((unsigned)s_[k] << shift) | (unsigned)(d_[k] & mask);
    }
  }
}

// One workgroup OWNS one bucket: LDS per-node degree histogram -> block-local
// exclusive scan -> coalesced (start,deg) int2 writes -> LDS-cursor CSR placement.
__global__ __launch_bounds__(512) void fill_csr4_kernel(
    const unsigned* __restrict__ ebuf, const int* __restrict__ bend,
    int shift, int N, int2* __restrict__ sd, int* __restrict__ csr_src)
{
  __shared__ int cnt[4096];               // supports shift <= 12
  __shared__ int psum[512];
  int b = blockIdx.x;
  int t = threadIdx.x;
  int bsz = 1 << shift;
  int mask = bsz - 1;
  int nbase = b << shift;
  for (int i = t; i < bsz; i += 512) cnt[i] = 0;
  __syncthreads();
  int gs = (b == 0) ? 0 : bend[b - 1];
  int ge = bend[b];
  for (int e = gs + t; e < ge; e += 512)
    atomicAdd(&cnt[ebuf[e] & mask], 1);
  __syncthreads();
  // two-level exclusive scan over cnt[0..bsz)
  int k = bsz >> 9;                       // elems per thread (>=1)
  int base = t * k;
  int loc = 0;
  for (int j = 0; j < k; ++j) loc += cnt[base + j];
  psum[t] = loc;
  __syncthreads();
  for (int off = 1; off < 512; off <<= 1){
    int x = (t >= off) ? psum[t - off] : 0;
    __syncthreads();
    psum[t] += x;
    __syncthreads();
  }
  int run = gs + psum[t] - loc;           // global exclusive prefix for chunk
  for (int j = 0; j < k; ++j){
    int node = nbase + base + j;
    int c = cnt[base + j];
    cnt[base + j] = run;                  // becomes placement cursor
    if (node < N) sd[node] = make_int2(run, c);
    run += c;
  }
  __syncthreads();
  for (int e = gs + t; e < ge; e += 512){
    unsigned v = ebuf[e];
    int slot = atomicAdd(&cnt[v & mask], 1);
    csr_src[slot] = (int)(v >> shift);
  }
}

// f = h @ W (32x32) stored as FP16 (64B/row -> 1 line per edge gather),
// el/er = per-head dot with al/ar in fp32. One thread per node.
__global__ __launch_bounds__(256) void fc_kernel(
    const float* __restrict__ hin, const int* __restrict__ nid,
    const float* __restrict__ W, const float* __restrict__ al, const float* __restrict__ ar,
    int n, __half* __restrict__ fh, float* __restrict__ el, float* __restrict__ er)
{
  __shared__ __align__(16) float Ws[1024];
  __shared__ float als[32], ars[32];
  int t = threadIdx.x;
  for (int i = t; i < 1024; i += 256) Ws[i] = W[i];
  if (t < 32){ als[t] = al[t]; ars[t] = ar[t]; }
  __syncthreads();
  int i = blockIdx.x * 256 + t;
  if (i >= n) return;
  long row = nid ? (long)nid[i] : (long)i;
  const float4* hp = (const float4*)(hin + row * 32);
  float h[32];
  #pragma unroll
  for (int q = 0; q < 8; ++q){
    float4 v = hp[q];
    h[4*q+0] = v.x; h[4*q+1] = v.y; h[4*q+2] = v.z; h[4*q+3] = v.w;
  }
  float fv[32];
  #pragma unroll
  for (int j = 0; j < 32; j += 4){
    float ax = 0.f, ay = 0.f, az = 0.f, aw = 0.f;
    #pragma unroll
    for (int k = 0; k < 32; ++k){
      float hk = h[k];
      float4 w = *(const float4*)&Ws[k*32 + j];
      ax += hk * w.x; ay += hk * w.y; az += hk * w.z; aw += hk * w.w;
    }
    fv[j] = ax; fv[j+1] = ay; fv[j+2] = az; fv[j+3] = aw;
  }
  __half hrow[32];
  #pragma unroll
  for (int j = 0; j < 32; ++j) hrow[j] = __float2half_rn(fv[j]);
  float4* fp = (float4*)(fh + (size_t)i * 32);
  #pragma unroll
  for (int q = 0; q < 4; ++q) fp[q] = ((const float4*)hrow)[q];
  float elv[4], erv[4];
  #pragma unroll
  for (int hh = 0; hh < 4; ++hh){
    float a = 0.f, b = 0.f;
    #pragma unroll
    for (int d = 0; d < 8; ++d){
      a += fv[hh*8 + d] * als[hh*8 + d];
      b += fv[hh*8 + d] * ars[hh*8 + d];
    }
    elv[hh] = a; erv[hh] = b;
  }
  *(float4*)(el + (size_t)i * 4) = make_float4(elv[0], elv[1], elv[2], elv[3]);
  *(float4*)(er + (size_t)i * 4) = make_float4(erv[0], erv[1], erv[2], erv[3]);
}

// One wave per dst node, fused softmax+gather.
// Pass 1 is lane-parallel over (edge,head): lane=(e,hh), e=lane>>2, hh=lane&3.
//   x = exp(lrelu(el[u][hh]+er[v][hh])) stored RAW in LDS; denominator reduce is
//   4 shuffle-adds (strides 4..32); normalization folds into the epilogue.
// Pass 2: 8 lanes per edge (fp16 col-quad), o4 = sum x*f; out = relu(o4*r + b).
__global__ __launch_bounds__(256) void gat_agg_kernel(
    const int* __restrict__ csr_src, const int2* __restrict__ sd,
    const __half* __restrict__ fh, const float* __restrict__ el, const float* __restrict__ er,
    const float* __restrict__ bias, int n, float* __restrict__ hout)
{
  __shared__ float x_s[4][256];           // [wave][e*4+hh], e<64
  int wid  = threadIdx.x >> 6;
  int lane = threadIdx.x & 63;
  int v = blockIdx.x * 4 + wid;
  if (v >= n) return;
  int2 sdv = sd[v];
  int s = sdv.x, d = sdv.y;

  if (d > 64){
    // slow path: 3-pass global recompute (statistically never for Poisson(16))
    float4 er4 = *(const float4*)(er + (size_t)v * 4);
    int col  = lane & 31;
    int half = lane >> 5;
    int head = col >> 3;
    float m0 = -1e30f, m1 = -1e30f, m2 = -1e30f, m3 = -1e30f;
    for (int i = lane; i < d; i += 64){
      int u = csr_src[s + i];
      float4 e4 = *(const float4*)(el + (size_t)u * 4);
      m0 = fmaxf(m0, lrelu(e4.x + er4.x));
      m1 = fmaxf(m1, lrelu(e4.y + er4.y));
      m2 = fmaxf(m2, lrelu(e4.z + er4.z));
      m3 = fmaxf(m3, lrelu(e4.w + er4.w));
    }
    #pragma unroll
    for (int off = 32; off >= 1; off >>= 1){
      m0 = fmaxf(m0, __shfl_xor(m0, off));
      m1 = fmaxf(m1, __shfl_xor(m1, off));
      m2 = fmaxf(m2, __shfl_xor(m2, off));
      m3 = fmaxf(m3, __shfl_xor(m3, off));
    }
    float s0 = 0.f, s1 = 0.f, s2 = 0.f, s3 = 0.f;
    for (int i = lane; i < d; i += 64){
      int u = csr_src[s + i];
      float4 e4 = *(const float4*)(el + (size_t)u * 4);
      s0 += expf(lrelu(e4.x + er4.x) - m0);
      s1 += expf(lrelu(e4.y + er4.y) - m1);
      s2 += expf(lrelu(e4.z + er4.z) - m2);
      s3 += expf(lrelu(e4.w + er4.w) - m3);
    }
    #pragma unroll
    for (int off = 32; off >= 1; off >>= 1){
      s0 += __shfl_xor(s0, off);
      s1 += __shfl_xor(s1, off);
      s2 += __shfl_xor(s2, off);
      s3 += __shfl_xor(s3, off);
    }
    float me  = head == 0 ? m0 : head == 1 ? m1 : head == 2 ? m2 : m3;
    float se  = head == 0 ? s0 : head == 1 ? s1 : head == 2 ? s2 : s3;
    float re  = 1.f / se;
    float ere = head == 0 ? er4.x : head == 1 ? er4.y : head == 2 ? er4.z : er4.w;
    float acc = 0.f;
    for (int i = half; i < d; i += 2){
      int u = csr_src[s + i];
      float e = lrelu(el[(size_t)u * 4 + head] + ere);
      float alpha = expf(e - me) * re;
      acc = fmaf(alpha, __half2float(fh[(size_t)u * 32 + col]), acc);
    }
    acc += __shfl_xor(acc, 32);
    if (lane < 32){
      float o = acc + bias[col];
      hout[(size_t)v * 32 + col] = fmaxf(o, 0.f);
    }
    return;
  }

  // ---- fast path (d <= 64) ----
  int hh = lane & 3;
  int e0 = lane >> 2;
  float erh = er[(size_t)v * 4 + hh];      // 16B row broadcast across wave
  float* xw = x_s[wid];
  float ssum = 0.f;
  for (int k = 0; k < d; k += 16){
    int e = e0 + k;                        // e < 64 always
    float x = 0.f;
    if (e < d){
      int u = csr_src[s + e];              // 4 lanes share address
      float lv = el[(size_t)u * 4 + hh];   // scalar 4B, 16B per edge-group
      x = __expf(lrelu(lv + erh));
    }
    xw[e * 4 + hh] = x;
    ssum += x;
  }
  #pragma unroll
  for (int off = 4; off < 64; off <<= 1)
    ssum += __shfl_xor(ssum, off);         // reduce over e, heads in low bits
  float r = d > 0 ? 1.f / ssum : 0.f;
  // DS ops of a wave complete in order; stop compiler reordering and drain
  // LDS before cross-lane reads. Wave-local data: no block barrier needed.
  asm volatile("s_waitcnt lgkmcnt(0)" ::: "memory");

  int cq    = lane & 7;    // col-quad: cols 4cq..4cq+3
  int g     = lane >> 3;   // edge group 0..7
  int headq = cq >> 1;     // head of this col-quad
  float4 o4 = make_float4(0.f, 0.f, 0.f, 0.f);
  for (int i = g; i < d; i += 8){
    int u = csr_src[s + i];                        // 8-lane broadcast (L1-hot)
    float a = xw[i * 4 + headq];
    uint2 raw = *(const uint2*)(fh + ((size_t)u << 5) + (cq << 2));
    float2 f01 = __half22float2(*(const __half2*)&raw.x);
    float2 f23 = __half22float2(*(const __half2*)&raw.y);
    o4.x = fmaf(a, f01.x, o4.x);
    o4.y = fmaf(a, f01.y, o4.y);
    o4.z = fmaf(a, f23.x, o4.z);
    o4.w = fmaf(a, f23.y, o4.w);
  }
  #pragma unroll
  for (int off = 32; off >= 8; off >>= 1){
    o4.x += __shfl_xor(o4.x, off);
    o4.y += __shfl_xor(o4.y, off);
    o4.z += __shfl_xor(o4.z, off);
    o4.w += __shfl_xor(o4.w, off);
  }
  float rh = __shfl(r, headq);             // lane 'headq' holds head headq's 1/sum
  if (lane < 8){
    float4 b4 = *(const float4*)(bias + cq * 4);
    float4 rr;
    rr.x = fmaxf(fmaf(o4.x, rh, b4.x), 0.f);
    rr.y = fmaxf(fmaf(o4.y, rh, b4.y), 0.f);
    rr.z = fmaxf(fmaf(o4.z, rh, b4.z), 0.f);
    rr.w = fmaxf(fmaf(o4.w, rh, b4.w), 0.f);
    *(float4*)(hout + (size_t)v * 32 + cq * 4) = rr;
  }
}

__device__ int lower_bound_dev(const int* a, int n, int key){
  int lo = 0, hi = n;
  while (lo < hi){
    int mid = (lo + hi) >> 1;
    if (a[mid] < key) lo = mid + 1; else hi = mid;
  }
  return lo;
}

// 8 slices per graph, atomic partial sums into hg (hg pre-zeroed).
__global__ void pool_kernel(const float* __restrict__ hout, const int* __restrict__ gid,
                            int n, float* __restrict__ hg){
  __shared__ int lohi[2];
  int g  = blockIdx.x >> 3;
  int sl = blockIdx.x & 7;
  int t = threadIdx.x;
  if (t < 2) lohi[t] = lower_bound_dev(gid, n, g + t);
  __syncthreads();
  int lo = lohi[0], hi = lohi[1];
  int cnt = hi - lo;
  if (cnt <= 0) return;
  int chunk = (cnt + 7) >> 3;
  int rlo = lo + sl * chunk;
  int rhi = min(rlo + chunk, hi);
  if (rlo >= rhi) return;
  int col = t & 31, r0 = t >> 5;
  float acc = 0.f;
  for (int r = rlo + r0; r < rhi; r += 8)
    acc += hout[(size_t)r * 32 + col];
  __shared__ float red[256];
  red[t] = acc; __syncthreads();
  if (t < 128) red[t] += red[t + 128];
  __syncthreads();
  if (t < 64) red[t] += red[t + 64];
  __syncthreads();
  if (t < 32) atomicAdd(&hg[g * 32 + t], red[t] + red[t + 32]);
}

// Scorer MLP; folds the mean-pool divide (counts via binary search on gid).
__global__ void score_kernel(const float* __restrict__ hg, const int* __restrict__ gid, int n,
                             const float* __restrict__ sw1, const float* __restrict__ sb1,
                             const float* __restrict__ sw2, const float* __restrict__ sb2,
                             int B, float* __restrict__ out){
  int g = blockIdx.x * blockDim.x + threadIdx.x;
  if (g >= B) return;
  int lo = lower_bound_dev(gid, n, g);
  int hi = lower_bound_dev(gid, n, g + 1);
  float inv = 1.f / fmaxf((float)(hi - lo), 1.f);
  float hvec[32];
  const float4* hp = (const float4*)(hg + g * 32);
  #pragma unroll
  for (int q = 0; q < 8; ++q){
    float4 v = hp[q];
    hvec[4*q+0] = v.x * inv; hvec[4*q+1] = v.y * inv;
    hvec[4*q+2] = v.z * inv; hvec[4*q+3] = v.w * inv;
  }
  float o = sb2[0];
  #pragma unroll
  for (int j = 0; j < 32; ++j){
    float a = sb1[j];
    #pragma unroll
    for (int k = 0; k < 32; ++k) a += hvec[k] * sw1[k*32 + j];
    o += fmaxf(a, 0.f) * sw2[j];
  }
  out[g] = o;
}

extern "C" void kernel_launch(void* const* d_in, const int* in_sizes, int n_in,
                              void* d_out, int out_size, void* d_ws, size_t ws_size,
                              hipStream_t stream)
{
  const int*   node_ids = (const int*)d_in[0];
  const int*   srcp     = (const int*)d_in[1];
  const int*   dstp     = (const int*)d_in[2];
  const int*   gid      = (const int*)d_in[3];
  const float* emb      = (const float*)d_in[4];
  const float* W0       = (const float*)d_in[5];
  const float* al0      = (const float*)d_in[6];
  const float* ar0      = (const float*)d_in[7];
  const float* b0       = (const float*)d_in[8];
  const float* W1       = (const float*)d_in[9];
  const float* al1      = (const float*)d_in[10];
  const float* ar1      = (const float*)d_in[11];
  const float* b1       = (const float*)d_in[12];
  const float* sw1      = (const float*)d_in[13];
  const float* sb1      = (const float*)d_in[14];
  const float* sw2      = (const float*)d_in[15];
  const float* sb2      = (const float*)d_in[16];

  int N = in_sizes[0];
  int E = in_sizes[1];
  int B = out_size;           // output is [B,1] float32
  float* out = (float*)d_out;

  // Workspace carve-out (256B aligned)
  char* p = (char*)d_ws;
  auto alloc = [&](size_t bytes) -> char* {
    char* r = p;
    p += (bytes + 255) & ~(size_t)255;
    return r;
  };
  // Coarse dst-buckets: one workgroup per bucket in the fill pass.
  int shift = 9;
  while ((((long)N + (1L << shift) - 1) >> shift) > 512 && shift < 12) ++shift;
  int nbk = (int)(((long)N + (1L << shift) - 1) >> shift);

  int2*     sd      = (int2*)alloc((size_t)N * 8);
  int*      bcount  = (int*)alloc((size_t)nbk * 4);
  int*      gcur    = (int*)alloc((size_t)nbk * 4);
  int*      csr_src = (int*)alloc((size_t)E * 4);
  float*    el      = (float*)alloc((size_t)N * 16);
  float*    er      = (float*)alloc((size_t)N * 16);
  size_t fbytes  = (size_t)N * 64;          // fp16 f rows
  size_t ebytes  = (size_t)E * 4;
  __half*   fh      = (__half*)alloc(fbytes > ebytes ? fbytes : ebytes);
  float*    h       = (float*)alloc((size_t)N * 128);
  float*    hg      = (float*)alloc((size_t)B * 32 * 4);
  unsigned* ebuf    = (unsigned*)fh;  // disjoint lifetime: consumed before fc writes fh

  hipMemsetAsync(bcount, 0, (size_t)nbk * 4, stream);
  hipMemsetAsync(hg, 0, (size_t)B * 32 * 4, stream);

  int eb4k = (E + 4095) / 4096;
  bhist_kernel<<<eb4k, 256, 0, stream>>>(dstp, E, shift, nbk, bcount);
  bscan_kernel<<<1, 512, 0, stream>>>(bcount, nbk, gcur);
  bin_kernel<<<eb4k, 256, 0, stream>>>(srcp, dstp, E, shift, nbk, gcur, ebuf);
  // after bin: gcur[b] == end offset of bucket b
  fill_csr4_kernel<<<nbk, 512, 0, stream>>>(ebuf, gcur, shift, N, sd, csr_src);

  int nblk = (N + 255) / 256;
  int ablk = (N + 3) / 4;
  // Layer 0: h_in = emb[node_ids]
  fc_kernel<<<nblk, 256, 0, stream>>>(emb, node_ids, W0, al0, ar0, N, fh, el, er);
  gat_agg_kernel<<<ablk, 256, 0, stream>>>(csr_src, sd, fh, el, er, b0, N, h);
  // Layer 1: h_in = h
  fc_kernel<<<nblk, 256, 0, stream>>>(h, nullptr, W1, al1, ar1, N, fh, el, er);
  gat_agg_kernel<<<ablk, 256, 0, stream>>>(csr_src, sd, fh, el, er, b1, N, h);

  pool_kernel<<<B * 8, 256, 0, stream>>>(h, gid, N, hg);
  score_kernel<<<1, 64, 0, stream>>>(hg, gid, N, sw1, sb1, sw2, sb2, B, out);
}

// Round 10
// 376.885 us; speedup vs baseline: 1.6033x; 1.0852x over previous
//
#include <hip/hip_runtime.h>
#include <hip/hip_fp16.h>
#include <math.h>

__device__ __forceinline__ float lrelu(float x){ return x > 0.f ? x : 0.2f * x; }

// Per-block LDS histogram of dst-buckets -> few global atomics per block.
__global__ __launch_bounds__(256) void bhist_kernel(
    const int* __restrict__ dst, int E, int shift, int nbk, int* __restrict__ bcount)
{
  __shared__ int hist[512];
  int t = threadIdx.x;
  for (int i = t; i < nbk; i += 256) hist[i] = 0;
  __syncthreads();
  long base = (long)blockIdx.x * 4096;
  #pragma unroll
  for (int k = 0; k < 16; ++k){
    long e = base + (long)k * 256 + t;
    if (e < E) atomicAdd(&hist[dst[e] >> shift], 1);
  }
  __syncthreads();
  for (int i = t; i < nbk; i += 256){
    int v = hist[i];
    if (v) atomicAdd(&bcount[i], v);
  }
}

// Single-block exclusive scan of bucket counts -> bucket start cursors.
__global__ __launch_bounds__(512) void bscan_kernel(
    const int* __restrict__ bcount, int nbk, int* __restrict__ gcur)
{
  __shared__ int sh[512];
  int t = threadIdx.x;
  int v = (t < nbk) ? bcount[t] : 0;
  sh[t] = v; __syncthreads();
  for (int off = 1; off < 512; off <<= 1){
    int x = (t >= off) ? sh[t - off] : 0;
    __syncthreads();
    sh[t] += x;
    __syncthreads();
  }
  if (t < nbk) gcur[t] = sh[t] - v;   // exclusive bucket start
}

// Bin edges by coarse dst-bucket (packed u32: src<<shift | local_dst).
// After this kernel, gcur[b] == END offset of bucket b's edge range.
__global__ __launch_bounds__(256) void bin_kernel(
    const int* __restrict__ src, const int* __restrict__ dst, int E, int shift, int nbk,
    int* __restrict__ gcur, unsigned* __restrict__ ebuf)
{
  __shared__ int hist[512];
  __shared__ int lbase[512];
  int t = threadIdx.x;
  int mask = (1 << shift) - 1;
  long base = (long)blockIdx.x * 4096;
  for (int i = t; i < nbk; i += 256) hist[i] = 0;
  __syncthreads();
  int s_[16], d_[16];
  #pragma unroll
  for (int k = 0; k < 16; ++k){
    long e = base + (long)k * 256 + t;
    if (e < E){
      s_[k] = src[e]; d_[k] = dst[e];
      atomicAdd(&hist[d_[k] >> shift], 1);
    } else d_[k] = -1;
  }
  __syncthreads();
  for (int i = t; i < nbk; i += 256){
    lbase[i] = atomicAdd(&gcur[i], hist[i]);
    hist[i] = 0;
  }
  __syncthreads();
  #pragma unroll
  for (int k = 0; k < 16; ++k){
    if (d_[k] >= 0){
      int b = d_[k] >> shift;
      int r = atomicAdd(&hist[b], 1);
      ebuf[lbase[b] + r] = ((unsigned)s_[k] << shift) | (unsigned)(d_[k] & mask);
    }
  }
}

// One workgroup OWNS one bucket: LDS per-node degree histogram -> block-local
// exclusive scan -> coalesced (start,deg) int2 writes -> LDS-cursor CSR placement.
__global__ __launch_bounds__(512) void fill_csr4_kernel(
    const unsigned* __restrict__ ebuf, const int* __restrict__ bend,
    int shift, int N, int2* __restrict__ sd, int* __restrict__ csr_src)
{
  __shared__ int cnt[4096];               // supports shift <= 12
  __shared__ int psum[512];
  int b = blockIdx.x;
  int t = threadIdx.x;
  int bsz = 1 << shift;
  int mask = bsz - 1;
  int nbase = b << shift;
  for (int i = t; i < bsz; i += 512) cnt[i] = 0;
  __syncthreads();
  int gs = (b == 0) ? 0 : bend[b - 1];
  int ge = bend[b];
  for (int e = gs + t; e < ge; e += 512)
    atomicAdd(&cnt[ebuf[e] & mask], 1);
  __syncthreads();
  // two-level exclusive scan over cnt[0..bsz)
  int k = bsz >> 9;                       // elems per thread (>=1)
  int base = t * k;
  int loc = 0;
  for (int j = 0; j < k; ++j) loc += cnt[base + j];
  psum[t] = loc;
  __syncthreads();
  for (int off = 1; off < 512; off <<= 1){
    int x = (t >= off) ? psum[t - off] : 0;
    __syncthreads();
    psum[t] += x;
    __syncthreads();
  }
  int run = gs + psum[t] - loc;           // global exclusive prefix for chunk
  for (int j = 0; j < k; ++j){
    int node = nbase + base + j;
    int c = cnt[base + j];
    cnt[base + j] = run;                  // becomes placement cursor
    if (node < N) sd[node] = make_int2(run, c);
    run += c;
  }
  __syncthreads();
  for (int e = gs + t; e < ge; e += 512){
    unsigned v = ebuf[e];
    int slot = atomicAdd(&cnt[v & mask], 1);
    csr_src[slot] = (int)(v >> shift);
  }
}

// f = h @ W (32x32) stored as FP16 (64B/row -> 1 line per edge gather),
// el/er = per-head dot with al/ar in fp32. One thread per node.
// T = float (layer 0: emb rows) or __half (layer 1: fp16 h rows).
template <typename T>
__global__ __launch_bounds__(256) void fc_kernel(
    const T* __restrict__ hin, const int* __restrict__ nid,
    const float* __restrict__ W, const float* __restrict__ al, const float* __restrict__ ar,
    int n, __half* __restrict__ fh, float* __restrict__ el, float* __restrict__ er)
{
  __shared__ __align__(16) float Ws[1024];
  __shared__ float als[32], ars[32];
  int t = threadIdx.x;
  for (int i = t; i < 1024; i += 256) Ws[i] = W[i];
  if (t < 32){ als[t] = al[t]; ars[t] = ar[t]; }
  __syncthreads();
  int i = blockIdx.x * 256 + t;
  if (i >= n) return;
  long row = nid ? (long)nid[i] : (long)i;
  float h[32];
  if (sizeof(T) == 4){
    const float4* hp = (const float4*)((const float*)hin + row * 32);
    #pragma unroll
    for (int q = 0; q < 8; ++q){
      float4 v = hp[q];
      h[4*q+0] = v.x; h[4*q+1] = v.y; h[4*q+2] = v.z; h[4*q+3] = v.w;
    }
  } else {
    const uint2* hp = (const uint2*)((const __half*)hin + row * 32);
    #pragma unroll
    for (int q = 0; q < 8; ++q){
      uint2 raw = hp[q];
      float2 a = __half22float2(*(const __half2*)&raw.x);
      float2 b = __half22float2(*(const __half2*)&raw.y);
      h[4*q+0] = a.x; h[4*q+1] = a.y; h[4*q+2] = b.x; h[4*q+3] = b.y;
    }
  }
  float fv[32];
  #pragma unroll
  for (int j = 0; j < 32; j += 4){
    float ax = 0.f, ay = 0.f, az = 0.f, aw = 0.f;
    #pragma unroll
    for (int k = 0; k < 32; ++k){
      float hk = h[k];
      float4 w = *(const float4*)&Ws[k*32 + j];
      ax += hk * w.x; ay += hk * w.y; az += hk * w.z; aw += hk * w.w;
    }
    fv[j] = ax; fv[j+1] = ay; fv[j+2] = az; fv[j+3] = aw;
  }
  __half hrow[32];
  #pragma unroll
  for (int j = 0; j < 32; ++j) hrow[j] = __float2half_rn(fv[j]);
  float4* fp = (float4*)(fh + (size_t)i * 32);
  #pragma unroll
  for (int q = 0; q < 4; ++q) fp[q] = ((const float4*)hrow)[q];
  float elv[4], erv[4];
  #pragma unroll
  for (int hh = 0; hh < 4; ++hh){
    float a = 0.f, b = 0.f;
    #pragma unroll
    for (int d = 0; d < 8; ++d){
      a += fv[hh*8 + d] * als[hh*8 + d];
      b += fv[hh*8 + d] * ars[hh*8 + d];
    }
    elv[hh] = a; erv[hh] = b;
  }
  *(float4*)(el + (size_t)i * 4) = make_float4(elv[0], elv[1], elv[2], elv[3]);
  *(float4*)(er + (size_t)i * 4) = make_float4(erv[0], erv[1], erv[2], erv[3]);
}

// One wave per dst node, fused softmax+gather, latency-overlapped:
//  1) pass-1 el gathers issue first (lane=(e,hh)), exp -> LDS raw x
//  2) pass-2 csr+fh rows PREFETCH into registers (independent of softmax)
//     while the ssum shuffle-reduce completes -> ~3 overlapped round trips
//  3) FMA from registers; normalization folded into epilogue; fp16 output.
__global__ __launch_bounds__(256) void gat_agg_kernel(
    const int* __restrict__ csr_src, const int2* __restrict__ sd,
    const __half* __restrict__ fh, const float* __restrict__ el, const float* __restrict__ er,
    const float* __restrict__ bias, int n, __half* __restrict__ hout)
{
  __shared__ float x_s[4][256];           // [wave][e*4+hh], e<64
  int wid  = threadIdx.x >> 6;
  int lane = threadIdx.x & 63;
  int v = blockIdx.x * 4 + wid;
  if (v >= n) return;
  int2 sdv = sd[v];
  int s = sdv.x, d = sdv.y;

  if (d > 64){
    // slow path: 3-pass global recompute (statistically never for Poisson(16))
    float4 er4 = *(const float4*)(er + (size_t)v * 4);
    int col  = lane & 31;
    int half = lane >> 5;
    int head = col >> 3;
    float m0 = -1e30f, m1 = -1e30f, m2 = -1e30f, m3 = -1e30f;
    for (int i = lane; i < d; i += 64){
      int u = csr_src[s + i];
      float4 e4 = *(const float4*)(el + (size_t)u * 4);
      m0 = fmaxf(m0, lrelu(e4.x + er4.x));
      m1 = fmaxf(m1, lrelu(e4.y + er4.y));
      m2 = fmaxf(m2, lrelu(e4.z + er4.z));
      m3 = fmaxf(m3, lrelu(e4.w + er4.w));
    }
    #pragma unroll
    for (int off = 32; off >= 1; off >>= 1){
      m0 = fmaxf(m0, __shfl_xor(m0, off));
      m1 = fmaxf(m1, __shfl_xor(m1, off));
      m2 = fmaxf(m2, __shfl_xor(m2, off));
      m3 = fmaxf(m3, __shfl_xor(m3, off));
    }
    float s0 = 0.f, s1 = 0.f, s2 = 0.f, s3 = 0.f;
    for (int i = lane; i < d; i += 64){
      int u = csr_src[s + i];
      float4 e4 = *(const float4*)(el + (size_t)u * 4);
      s0 += expf(lrelu(e4.x + er4.x) - m0);
      s1 += expf(lrelu(e4.y + er4.y) - m1);
      s2 += expf(lrelu(e4.z + er4.z) - m2);
      s3 += expf(lrelu(e4.w + er4.w) - m3);
    }
    #pragma unroll
    for (int off = 32; off >= 1; off >>= 1){
      s0 += __shfl_xor(s0, off);
      s1 += __shfl_xor(s1, off);
      s2 += __shfl_xor(s2, off);
      s3 += __shfl_xor(s3, off);
    }
    float me  = head == 0 ? m0 : head == 1 ? m1 : head == 2 ? m2 : m3;
    float se  = head == 0 ? s0 : head == 1 ? s1 : head == 2 ? s2 : s3;
    float re  = 1.f / se;
    float ere = head == 0 ? er4.x : head == 1 ? er4.y : head == 2 ? er4.z : er4.w;
    float acc = 0.f;
    for (int i = half; i < d; i += 2){
      int u = csr_src[s + i];
      float e = lrelu(el[(size_t)u * 4 + head] + ere);
      float alpha = expf(e - me) * re;
      acc = fmaf(alpha, __half2float(fh[(size_t)u * 32 + col]), acc);
    }
    acc += __shfl_xor(acc, 32);
    if (lane < 32)
      hout[(size_t)v * 32 + col] = __float2half_rn(fmaxf(acc + bias[col], 0.f));
    return;
  }

  // ---- fast path (d <= 64) ----
  int hh = lane & 3;
  int e0 = lane >> 2;
  float erh = er[(size_t)v * 4 + hh];      // 16B row broadcast across wave
  float* xw = x_s[wid];
  float ssum = 0.f;
  for (int k = 0; k < d; k += 16){
    int e = e0 + k;                        // e < 64 always
    float x = 0.f;
    if (e < d){
      int u = csr_src[s + e];              // 4 lanes share address
      float lv = el[(size_t)u * 4 + hh];   // scalar 4B, 16B per edge-group
      x = __expf(lrelu(lv + erh));
    }
    xw[e * 4 + hh] = x;
    ssum += x;
  }

  // prefetch pass-2 operands into registers while softmax reduce finishes;
  // static (unrolled) indices keep u_r/raw in VGPRs (no scratch).
  int cq    = lane & 7;    // col-quad: cols 4cq..4cq+3
  int g     = lane >> 3;   // edge group 0..7
  int headq = cq >> 1;     // head of this col-quad
  int   u_r[8];
  uint2 raw[8];
  #pragma unroll
  for (int it = 0; it < 8; ++it){
    int i = g + it * 8;
    if (i < d) u_r[it] = csr_src[s + i];   // L1-hot (just read in pass 1)
  }
  #pragma unroll
  for (int it = 0; it < 8; ++it){
    int i = g + it * 8;
    if (i < d) raw[it] = *(const uint2*)(fh + ((size_t)u_r[it] << 5) + (cq << 2));
  }

  #pragma unroll
  for (int off = 4; off < 64; off <<= 1)
    ssum += __shfl_xor(ssum, off);         // reduce over e, heads in low bits
  float r = d > 0 ? 1.f / ssum : 0.f;
  // DS ops of a wave complete in order; stop compiler reordering and drain
  // LDS before cross-lane reads. Wave-local data: no block barrier needed.
  asm volatile("s_waitcnt lgkmcnt(0)" ::: "memory");

  float4 o4 = make_float4(0.f, 0.f, 0.f, 0.f);
  #pragma unroll
  for (int it = 0; it < 8; ++it){
    int i = g + it * 8;
    if (i < d){
      float a = xw[i * 4 + headq];
      float2 f01 = __half22float2(*(const __half2*)&raw[it].x);
      float2 f23 = __half22float2(*(const __half2*)&raw[it].y);
      o4.x = fmaf(a, f01.x, o4.x);
      o4.y = fmaf(a, f01.y, o4.y);
      o4.z = fmaf(a, f23.x, o4.z);
      o4.w = fmaf(a, f23.y, o4.w);
    }
  }
  #pragma unroll
  for (int off = 32; off >= 8; off >>= 1){
    o4.x += __shfl_xor(o4.x, off);
    o4.y += __shfl_xor(o4.y, off);
    o4.z += __shfl_xor(o4.z, off);
    o4.w += __shfl_xor(o4.w, off);
  }
  float rh = __shfl(r, headq);             // lane 'headq' holds head headq's 1/sum
  if (lane < 8){
    float4 b4 = *(const float4*)(bias + cq * 4);
    __half2 h01 = __halves2half2(__float2half_rn(fmaxf(fmaf(o4.x, rh, b4.x), 0.f)),
                                 __float2half_rn(fmaxf(fmaf(o4.y, rh, b4.y), 0.f)));
    __half2 h23 = __halves2half2(__float2half_rn(fmaxf(fmaf(o4.z, rh, b4.z), 0.f)),
                                 __float2half_rn(fmaxf(fmaf(o4.w, rh, b4.w), 0.f)));
    uint2 pk;
    pk.x = *(unsigned*)&h01;
    pk.y = *(unsigned*)&h23;
    *(uint2*)(hout + (size_t)v * 32 + cq * 4) = pk;
  }
}

__device__ int lower_bound_dev(const int* a, int n, int key){
  int lo = 0, hi = n;
  while (lo < hi){
    int mid = (lo + hi) >> 1;
    if (a[mid] < key) lo = mid + 1; else hi = mid;
  }
  return lo;
}

// 8 slices per graph, atomic partial sums into hg (hg pre-zeroed). fp16 input.
__global__ void pool_kernel(const __half* __restrict__ hout, const int* __restrict__ gid,
                            int n, float* __restrict__ hg){
  __shared__ int lohi[2];
  int g  = blockIdx.x >> 3;
  int sl = blockIdx.x & 7;
  int t = threadIdx.x;
  if (t < 2) lohi[t] = lower_bound_dev(gid, n, g + t);
  __syncthreads();
  int lo = lohi[0], hi = lohi[1];
  int cnt = hi - lo;
  if (cnt <= 0) return;
  int chunk = (cnt + 7) >> 3;
  int rlo = lo + sl * chunk;
  int rhi = min(rlo + chunk, hi);
  if (rlo >= rhi) return;
  int col = t & 31, r0 = t >> 5;
  float acc = 0.f;
  for (int r = rlo + r0; r < rhi; r += 8)
    acc += __half2float(hout[(size_t)r * 32 + col]);
  __shared__ float red[256];
  red[t] = acc; __syncthreads();
  if (t < 128) red[t] += red[t + 128];
  __syncthreads();
  if (t < 64) red[t] += red[t + 64];
  __syncthreads();
  if (t < 32) atomicAdd(&hg[g * 32 + t], red[t] + red[t + 32]);
}

// Scorer MLP; folds the mean-pool divide (counts via binary search on gid).
__global__ void score_kernel(const float* __restrict__ hg, const int* __restrict__ gid, int n,
                             const float* __restrict__ sw1, const float* __restrict__ sb1,
                             const float* __restrict__ sw2, const float* __restrict__ sb2,
                             int B, float* __restrict__ out){
  int g = blockIdx.x * blockDim.x + threadIdx.x;
  if (g >= B) return;
  int lo = lower_bound_dev(gid, n, g);
  int hi = lower_bound_dev(gid, n, g + 1);
  float inv = 1.f / fmaxf((float)(hi - lo), 1.f);
  float hvec[32];
  const float4* hp = (const float4*)(hg + g * 32);
  #pragma unroll
  for (int q = 0; q < 8; ++q){
    float4 v = hp[q];
    hvec[4*q+0] = v.x * inv; hvec[4*q+1] = v.y * inv;
    hvec[4*q+2] = v.z * inv; hvec[4*q+3] = v.w * inv;
  }
  float o = sb2[0];
  #pragma unroll
  for (int j = 0; j < 32; ++j){
    float a = sb1[j];
    #pragma unroll
    for (int k = 0; k < 32; ++k) a += hvec[k] * sw1[k*32 + j];
    o += fmaxf(a, 0.f) * sw2[j];
  }
  out[g] = o;
}

extern "C" void kernel_launch(void* const* d_in, const int* in_sizes, int n_in,
                              void* d_out, int out_size, void* d_ws, size_t ws_size,
                              hipStream_t stream)
{
  const int*   node_ids = (const int*)d_in[0];
  const int*   srcp     = (const int*)d_in[1];
  const int*   dstp     = (const int*)d_in[2];
  const int*   gid      = (const int*)d_in[3];
  const float* emb      = (const float*)d_in[4];
  const float* W0       = (const float*)d_in[5];
  const float* al0      = (const float*)d_in[6];
  const float* ar0      = (const float*)d_in[7];
  const float* b0       = (const float*)d_in[8];
  const float* W1       = (const float*)d_in[9];
  const float* al1      = (const float*)d_in[10];
  const float* ar1      = (const float*)d_in[11];
  const float* b1       = (const float*)d_in[12];
  const float* sw1      = (const float*)d_in[13];
  const float* sb1      = (const float*)d_in[14];
  const float* sw2      = (const float*)d_in[15];
  const float* sb2      = (const float*)d_in[16];

  int N = in_sizes[0];
  int E = in_sizes[1];
  int B = out_size;           // output is [B,1] float32
  float* out = (float*)d_out;

  // Workspace carve-out (256B aligned)
  char* p = (char*)d_ws;
  auto alloc = [&](size_t bytes) -> char* {
    char* r = p;
    p += (bytes + 255) & ~(size_t)255;
    return r;
  };
  // Coarse dst-buckets: one workgroup per bucket in the fill pass.
  int shift = 9;
  while ((((long)N + (1L << shift) - 1) >> shift) > 512 && shift < 12) ++shift;
  int nbk = (int)(((long)N + (1L << shift) - 1) >> shift);

  int2*     sd      = (int2*)alloc((size_t)N * 8);
  int*      bcount  = (int*)alloc((size_t)nbk * 4);
  int*      gcur    = (int*)alloc((size_t)nbk * 4);
  int*      csr_src = (int*)alloc((size_t)E * 4);
  float*    el      = (float*)alloc((size_t)N * 16);
  float*    er      = (float*)alloc((size_t)N * 16);
  size_t fbytes  = (size_t)N * 64;          // fp16 f rows
  size_t ebytes  = (size_t)E * 4;
  __half*   fh      = (__half*)alloc(fbytes > ebytes ? fbytes : ebytes);
  __half*   h       = (__half*)alloc((size_t)N * 64);   // fp16 h rows
  float*    hg      = (float*)alloc((size_t)B * 32 * 4);
  unsigned* ebuf    = (unsigned*)fh;  // disjoint lifetime: consumed before fc writes fh

  hipMemsetAsync(bcount, 0, (size_t)nbk * 4, stream);
  hipMemsetAsync(hg, 0, (size_t)B * 32 * 4, stream);

  int eb4k = (E + 4095) / 4096;
  bhist_kernel<<<eb4k, 256, 0, stream>>>(dstp, E, shift, nbk, bcount);
  bscan_kernel<<<1, 512, 0, stream>>>(bcount, nbk, gcur);
  bin_kernel<<<eb4k, 256, 0, stream>>>(srcp, dstp, E, shift, nbk, gcur, ebuf);
  // after bin: gcur[b] == end offset of bucket b
  fill_csr4_kernel<<<nbk, 512, 0, stream>>>(ebuf, gcur, shift, N, sd, csr_src);

  int nblk = (N + 255) / 256;
  int ablk = (N + 3) / 4;
  // Layer 0: h_in = emb[node_ids]
  fc_kernel<float><<<nblk, 256, 0, stream>>>(emb, node_ids, W0, al0, ar0, N, fh, el, er);
  gat_agg_kernel<<<ablk, 256, 0, stream>>>(csr_src, sd, fh, el, er, b0, N, h);
  // Layer 1: h_in = h (fp16)
  fc_kernel<__half><<<nblk, 256, 0, stream>>>(h, nullptr, W1, al1, ar1, N, fh, el, er);
  gat_agg_kernel<<<ablk, 256, 0, stream>>>(csr_src, sd, fh, el, er, b1, N, h);

  pool_kernel<<<B * 8, 256, 0, stream>>>(h, gid, N, hg);
  score_kernel<<<1, 64, 0, stream>>>(hg, gid, N, sw1, sb1, sw2, sb2, B, out);
}

// Round 11
// 344.652 us; speedup vs baseline: 1.7532x; 1.0935x over previous
//
#include <hip/hip_runtime.h>
#include <hip/hip_fp16.h>
#include <math.h>

__device__ __forceinline__ float lrelu(float x){ return x > 0.f ? x : 0.2f * x; }

// Per-block LDS histogram of dst-buckets -> few global atomics per block.
__global__ __launch_bounds__(256) void bhist_kernel(
    const int* __restrict__ dst, int E, int shift, int nbk, int* __restrict__ bcount)
{
  __shared__ int hist[512];
  int t = threadIdx.x;
  for (int i = t; i < nbk; i += 256) hist[i] = 0;
  __syncthreads();
  long base = (long)blockIdx.x * 4096;
  #pragma unroll
  for (int k = 0; k < 16; ++k){
    long e = base + (long)k * 256 + t;
    if (e < E) atomicAdd(&hist[dst[e] >> shift], 1);
  }
  __syncthreads();
  for (int i = t; i < nbk; i += 256){
    int v = hist[i];
    if (v) atomicAdd(&bcount[i], v);
  }
}

// Single-block exclusive scan of bucket counts -> bucket start cursors.
__global__ __launch_bounds__(512) void bscan_kernel(
    const int* __restrict__ bcount, int nbk, int* __restrict__ gcur)
{
  __shared__ int sh[512];
  int t = threadIdx.x;
  int v = (t < nbk) ? bcount[t] : 0;
  sh[t] = v; __syncthreads();
  for (int off = 1; off < 512; off <<= 1){
    int x = (t >= off) ? sh[t - off] : 0;
    __syncthreads();
    sh[t] += x;
    __syncthreads();
  }
  if (t < nbk) gcur[t] = sh[t] - v;   // exclusive bucket start
}

// Bin edges by coarse dst-bucket (packed u32: src<<shift | local_dst).
// After this kernel, gcur[b] == END offset of bucket b's edge range.
__global__ __launch_bounds__(256) void bin_kernel(
    const int* __restrict__ src, const int* __restrict__ dst, int E, int shift, int nbk,
    int* __restrict__ gcur, unsigned* __restrict__ ebuf)
{
  __shared__ int hist[512];
  __shared__ int lbase[512];
  int t = threadIdx.x;
  int mask = (1 << shift) - 1;
  long base = (long)blockIdx.x * 4096;
  for (int i = t; i < nbk; i += 256) hist[i] = 0;
  __syncthreads();
  int s_[16], d_[16];
  #pragma unroll
  for (int k = 0; k < 16; ++k){
    long e = base + (long)k * 256 + t;
    if (e < E){
      s_[k] = src[e]; d_[k] = dst[e];
      atomicAdd(&hist[d_[k] >> shift], 1);
    } else d_[k] = -1;
  }
  __syncthreads();
  for (int i = t; i < nbk; i += 256){
    lbase[i] = atomicAdd(&gcur[i], hist[i]);
    hist[i] = 0;
  }
  __syncthreads();
  #pragma unroll
  for (int k = 0; k < 16; ++k){
    if (d_[k] >= 0){
      int b = d_[k] >> shift;
      int r = atomicAdd(&hist[b], 1);
      ebuf[lbase[b] + r] = ((unsigned)s_[k] << shift) | (unsigned)(d_[k] & mask);
    }
  }
}

// One workgroup OWNS one bucket: LDS per-node degree histogram -> block-local
// exclusive scan -> coalesced (start,deg) int2 writes -> LDS-cursor CSR placement.
__global__ __launch_bounds__(512) void fill_csr4_kernel(
    const unsigned* __restrict__ ebuf, const int* __restrict__ bend,
    int shift, int N, int2* __restrict__ sd, int* __restrict__ csr_src)
{
  __shared__ int cnt[4096];               // supports shift <= 12
  __shared__ int psum[512];
  int b = blockIdx.x;
  int t = threadIdx.x;
  int bsz = 1 << shift;
  int mask = bsz - 1;
  int nbase = b << shift;
  for (int i = t; i < bsz; i += 512) cnt[i] = 0;
  __syncthreads();
  int gs = (b == 0) ? 0 : bend[b - 1];
  int ge = bend[b];
  for (int e = gs + t; e < ge; e += 512)
    atomicAdd(&cnt[ebuf[e] & mask], 1);
  __syncthreads();
  // two-level exclusive scan over cnt[0..bsz)
  int k = bsz >> 9;                       // elems per thread (>=1)
  int base = t * k;
  int loc = 0;
  for (int j = 0; j < k; ++j) loc += cnt[base + j];
  psum[t] = loc;
  __syncthreads();
  for (int off = 1; off < 512; off <<= 1){
    int x = (t >= off) ? psum[t - off] : 0;
    __syncthreads();
    psum[t] += x;
    __syncthreads();
  }
  int run = gs + psum[t] - loc;           // global exclusive prefix for chunk
  for (int j = 0; j < k; ++j){
    int node = nbase + base + j;
    int c = cnt[base + j];
    cnt[base + j] = run;                  // becomes placement cursor
    if (node < N) sd[node] = make_int2(run, c);
    run += c;
  }
  __syncthreads();
  for (int e = gs + t; e < ge; e += 512){
    unsigned v = ebuf[e];
    int slot = atomicAdd(&cnt[v & mask], 1);
    csr_src[slot] = (int)(v >> shift);
  }
}

// f = h @ W (32x32) stored as FP16 (64B/row -> 1 line per edge gather),
// el/er = per-head dot with al/ar in fp32. One thread per node.
// T = float (layer 0: emb rows) or __half (layer 1: fp16 h rows).
template <typename T>
__global__ __launch_bounds__(256) void fc_kernel(
    const T* __restrict__ hin, const int* __restrict__ nid,
    const float* __restrict__ W, const float* __restrict__ al, const float* __restrict__ ar,
    int n, __half* __restrict__ fh, float* __restrict__ el, float* __restrict__ er)
{
  __shared__ __align__(16) float Ws[1024];
  __shared__ float als[32], ars[32];
  int t = threadIdx.x;
  for (int i = t; i < 1024; i += 256) Ws[i] = W[i];
  if (t < 32){ als[t] = al[t]; ars[t] = ar[t]; }
  __syncthreads();
  int i = blockIdx.x * 256 + t;
  if (i >= n) return;
  long row = nid ? (long)nid[i] : (long)i;
  float h[32];
  if (sizeof(T) == 4){
    const float4* hp = (const float4*)((const float*)hin + row * 32);
    #pragma unroll
    for (int q = 0; q < 8; ++q){
      float4 v = hp[q];
      h[4*q+0] = v.x; h[4*q+1] = v.y; h[4*q+2] = v.z; h[4*q+3] = v.w;
    }
  } else {
    const uint2* hp = (const uint2*)((const __half*)hin + row * 32);
    #pragma unroll
    for (int q = 0; q < 8; ++q){
      uint2 raw = hp[q];
      float2 a = __half22float2(*(const __half2*)&raw.x);
      float2 b = __half22float2(*(const __half2*)&raw.y);
      h[4*q+0] = a.x; h[4*q+1] = a.y; h[4*q+2] = b.x; h[4*q+3] = b.y;
    }
  }
  float fv[32];
  #pragma unroll
  for (int j = 0; j < 32; j += 4){
    float ax = 0.f, ay = 0.f, az = 0.f, aw = 0.f;
    #pragma unroll
    for (int k = 0; k < 32; ++k){
      float hk = h[k];
      float4 w = *(const float4*)&Ws[k*32 + j];
      ax += hk * w.x; ay += hk * w.y; az += hk * w.z; aw += hk * w.w;
    }
    fv[j] = ax; fv[j+1] = ay; fv[j+2] = az; fv[j+3] = aw;
  }
  __half hrow[32];
  #pragma unroll
  for (int j = 0; j < 32; ++j) hrow[j] = __float2half_rn(fv[j]);
  float4* fp = (float4*)(fh + (size_t)i * 32);
  #pragma unroll
  for (int q = 0; q < 4; ++q) fp[q] = ((const float4*)hrow)[q];
  float elv[4], erv[4];
  #pragma unroll
  for (int hh = 0; hh < 4; ++hh){
    float a = 0.f, b = 0.f;
    #pragma unroll
    for (int d = 0; d < 8; ++d){
      a += fv[hh*8 + d] * als[hh*8 + d];
      b += fv[hh*8 + d] * ars[hh*8 + d];
    }
    elv[hh] = a; erv[hh] = b;
  }
  *(float4*)(el + (size_t)i * 4) = make_float4(elv[0], elv[1], elv[2], elv[3]);
  *(float4*)(er + (size_t)i * 4) = make_float4(erv[0], erv[1], erv[2], erv[3]);
}

// One wave per dst node, SINGLE-PASS fused softmax+gather.
// Deferred normalization: out = (sum_e x_e * f_e) / (sum_e x_e),
// x_e = exp(lrelu(el[u]+er[v])) computed lane-locally (8 lanes per edge,
// each owning a col-quad; el scalar load rides beside the fh quad load).
// No LDS, no fence, one csr read; critical path sd -> csr -> {el || fh} -> FMA.
// Chunked 8-deep register prefetch handles any degree uniformly.
__global__ __launch_bounds__(256) void gat_agg_kernel(
    const int* __restrict__ csr_src, const int2* __restrict__ sd,
    const __half* __restrict__ fh, const float* __restrict__ el, const float* __restrict__ er,
    const float* __restrict__ bias, int n, __half* __restrict__ hout)
{
  int wid  = threadIdx.x >> 6;
  int lane = threadIdx.x & 63;
  int v = blockIdx.x * 4 + wid;
  if (v >= n) return;
  int2 sdv = sd[v];
  int s = sdv.x, d = sdv.y;
  int cq    = lane & 7;    // col-quad: cols 4cq..4cq+3
  int g     = lane >> 3;   // edge group 0..7
  int headq = cq >> 1;     // head of this col-quad
  float erh = er[(size_t)v * 4 + headq];

  float4 o4 = make_float4(0.f, 0.f, 0.f, 0.f);
  float dsum = 0.f;
  for (int base = 0; base < d; base += 64){
    int   u_r[8];
    float lv[8];
    uint2 raw[8];
    #pragma unroll
    for (int it = 0; it < 8; ++it){
      int i = base + g + it * 8;
      if (i < d) u_r[it] = csr_src[s + i];      // 8-lane broadcast
    }
    #pragma unroll
    for (int it = 0; it < 8; ++it){
      int i = base + g + it * 8;
      if (i < d){
        lv[it]  = el[(size_t)u_r[it] * 4 + headq];                      // 4B in 16B row
        raw[it] = *(const uint2*)(fh + ((size_t)u_r[it] << 5) + (cq << 2)); // 8B of 64B row
      }
    }
    #pragma unroll
    for (int it = 0; it < 8; ++it){
      int i = base + g + it * 8;
      if (i < d){
        float x = __expf(lrelu(lv[it] + erh));
        dsum += x;
        float2 f01 = __half22float2(*(const __half2*)&raw[it].x);
        float2 f23 = __half22float2(*(const __half2*)&raw[it].y);
        o4.x = fmaf(x, f01.x, o4.x);
        o4.y = fmaf(x, f01.y, o4.y);
        o4.z = fmaf(x, f23.x, o4.z);
        o4.w = fmaf(x, f23.y, o4.w);
      }
    }
  }
  // reduce over the 8 edge-groups (cq preserved: offsets >= 8)
  #pragma unroll
  for (int off = 8; off < 64; off <<= 1){
    o4.x += __shfl_xor(o4.x, off);
    o4.y += __shfl_xor(o4.y, off);
    o4.z += __shfl_xor(o4.z, off);
    o4.w += __shfl_xor(o4.w, off);
    dsum += __shfl_xor(dsum, off);
  }
  if (lane < 8){
    float r = d > 0 ? 1.f / dsum : 0.f;
    float4 b4 = *(const float4*)(bias + cq * 4);
    __half2 h01 = __halves2half2(__float2half_rn(fmaxf(fmaf(o4.x, r, b4.x), 0.f)),
                                 __float2half_rn(fmaxf(fmaf(o4.y, r, b4.y), 0.f)));
    __half2 h23 = __halves2half2(__float2half_rn(fmaxf(fmaf(o4.z, r, b4.z), 0.f)),
                                 __float2half_rn(fmaxf(fmaf(o4.w, r, b4.w), 0.f)));
    uint2 pk;
    pk.x = *(unsigned*)&h01;
    pk.y = *(unsigned*)&h23;
    *(uint2*)(hout + (size_t)v * 32 + cq * 4) = pk;
  }
}

__device__ int lower_bound_dev(const int* a, int n, int key){
  int lo = 0, hi = n;
  while (lo < hi){
    int mid = (lo + hi) >> 1;
    if (a[mid] < key) lo = mid + 1; else hi = mid;
  }
  return lo;
}

// 8 slices per graph, atomic partial sums into hg (hg pre-zeroed). fp16 input.
__global__ void pool_kernel(const __half* __restrict__ hout, const int* __restrict__ gid,
                            int n, float* __restrict__ hg){
  __shared__ int lohi[2];
  int g  = blockIdx.x >> 3;
  int sl = blockIdx.x & 7;
  int t = threadIdx.x;
  if (t < 2) lohi[t] = lower_bound_dev(gid, n, g + t);
  __syncthreads();
  int lo = lohi[0], hi = lohi[1];
  int cnt = hi - lo;
  if (cnt <= 0) return;
  int chunk = (cnt + 7) >> 3;
  int rlo = lo + sl * chunk;
  int rhi = min(rlo + chunk, hi);
  if (rlo >= rhi) return;
  int col = t & 31, r0 = t >> 5;
  float acc = 0.f;
  for (int r = rlo + r0; r < rhi; r += 8)
    acc += __half2float(hout[(size_t)r * 32 + col]);
  __shared__ float red[256];
  red[t] = acc; __syncthreads();
  if (t < 128) red[t] += red[t + 128];
  __syncthreads();
  if (t < 64) red[t] += red[t + 64];
  __syncthreads();
  if (t < 32) atomicAdd(&hg[g * 32 + t], red[t] + red[t + 32]);
}

// Scorer MLP; folds the mean-pool divide (counts via binary search on gid).
__global__ void score_kernel(const float* __restrict__ hg, const int* __restrict__ gid, int n,
                             const float* __restrict__ sw1, const float* __restrict__ sb1,
                             const float* __restrict__ sw2, const float* __restrict__ sb2,
                             int B, float* __restrict__ out){
  int g = blockIdx.x * blockDim.x + threadIdx.x;
  if (g >= B) return;
  int lo = lower_bound_dev(gid, n, g);
  int hi = lower_bound_dev(gid, n, g + 1);
  float inv = 1.f / fmaxf((float)(hi - lo), 1.f);
  float hvec[32];
  const float4* hp = (const float4*)(hg + g * 32);
  #pragma unroll
  for (int q = 0; q < 8; ++q){
    float4 v = hp[q];
    hvec[4*q+0] = v.x * inv; hvec[4*q+1] = v.y * inv;
    hvec[4*q+2] = v.z * inv; hvec[4*q+3] = v.w * inv;
  }
  float o = sb2[0];
  #pragma unroll
  for (int j = 0; j < 32; ++j){
    float a = sb1[j];
    #pragma unroll
    for (int k = 0; k < 32; ++k) a += hvec[k] * sw1[k*32 + j];
    o += fmaxf(a, 0.f) * sw2[j];
  }
  out[g] = o;
}

extern "C" void kernel_launch(void* const* d_in, const int* in_sizes, int n_in,
                              void* d_out, int out_size, void* d_ws, size_t ws_size,
                              hipStream_t stream)
{
  const int*   node_ids = (const int*)d_in[0];
  const int*   srcp     = (const int*)d_in[1];
  const int*   dstp     = (const int*)d_in[2];
  const int*   gid      = (const int*)d_in[3];
  const float* emb      = (const float*)d_in[4];
  const float* W0       = (const float*)d_in[5];
  const float* al0      = (const float*)d_in[6];
  const float* ar0      = (const float*)d_in[7];
  const float* b0       = (const float*)d_in[8];
  const float* W1       = (const float*)d_in[9];
  const float* al1      = (const float*)d_in[10];
  const float* ar1      = (const float*)d_in[11];
  const float* b1       = (const float*)d_in[12];
  const float* sw1      = (const float*)d_in[13];
  const float* sb1      = (const float*)d_in[14];
  const float* sw2      = (const float*)d_in[15];
  const float* sb2      = (const float*)d_in[16];

  int N = in_sizes[0];
  int E = in_sizes[1];
  int B = out_size;           // output is [B,1] float32
  float* out = (float*)d_out;

  // Workspace carve-out (256B aligned)
  char* p = (char*)d_ws;
  auto alloc = [&](size_t bytes) -> char* {
    char* r = p;
    p += (bytes + 255) & ~(size_t)255;
    return r;
  };
  // Coarse dst-buckets: one workgroup per bucket in the fill pass.
  int shift = 9;
  while ((((long)N + (1L << shift) - 1) >> shift) > 512 && shift < 12) ++shift;
  int nbk = (int)(((long)N + (1L << shift) - 1) >> shift);

  int2*     sd      = (int2*)alloc((size_t)N * 8);
  int*      bcount  = (int*)alloc((size_t)nbk * 4);
  int*      gcur    = (int*)alloc((size_t)nbk * 4);
  int*      csr_src = (int*)alloc((size_t)E * 4);
  float*    el      = (float*)alloc((size_t)N * 16);
  float*    er      = (float*)alloc((size_t)N * 16);
  size_t fbytes  = (size_t)N * 64;          // fp16 f rows
  size_t ebytes  = (size_t)E * 4;
  __half*   fh      = (__half*)alloc(fbytes > ebytes ? fbytes : ebytes);
  __half*   h       = (__half*)alloc((size_t)N * 64);   // fp16 h rows
  float*    hg      = (float*)alloc((size_t)B * 32 * 4);
  unsigned* ebuf    = (unsigned*)fh;  // disjoint lifetime: consumed before fc writes fh

  hipMemsetAsync(bcount, 0, (size_t)nbk * 4, stream);
  hipMemsetAsync(hg, 0, (size_t)B * 32 * 4, stream);

  int eb4k = (E + 4095) / 4096;
  bhist_kernel<<<eb4k, 256, 0, stream>>>(dstp, E, shift, nbk, bcount);
  bscan_kernel<<<1, 512, 0, stream>>>(bcount, nbk, gcur);
  bin_kernel<<<eb4k, 256, 0, stream>>>(srcp, dstp, E, shift, nbk, gcur, ebuf);
  // after bin: gcur[b] == end offset of bucket b
  fill_csr4_kernel<<<nbk, 512, 0, stream>>>(ebuf, gcur, shift, N, sd, csr_src);

  int nblk = (N + 255) / 256;
  int ablk = (N + 3) / 4;
  // Layer 0: h_in = emb[node_ids]
  fc_kernel<float><<<nblk, 256, 0, stream>>>(emb, node_ids, W0, al0, ar0, N, fh, el, er);
  gat_agg_kernel<<<ablk, 256, 0, stream>>>(csr_src, sd, fh, el, er, b0, N, h);
  // Layer 1: h_in = h (fp16)
  fc_kernel<__half><<<nblk, 256, 0, stream>>>(h, nullptr, W1, al1, ar1, N, fh, el, er);
  gat_agg_kernel<<<ablk, 256, 0, stream>>>(csr_src, sd, fh, el, er, b1, N, h);

  pool_kernel<<<B * 8, 256, 0, stream>>>(h, gid, N, hg);
  score_kernel<<<1, 64, 0, stream>>>(hg, gid, N, sw1, sb1, sw2, sb2, B, out);
}

// Round 12
// 334.017 us; speedup vs baseline: 1.8090x; 1.0318x over previous
//
#include <hip/hip_runtime.h>
#include <hip/hip_fp16.h>
#include <math.h>

__device__ __forceinline__ float lrelu(float x){ return x > 0.f ? x : 0.2f * x; }

// Per-block LDS histogram of dst-buckets -> few global atomics per block.
__global__ __launch_bounds__(256) void bhist_kernel(
    const int* __restrict__ dst, int E, int shift, int nbk, int* __restrict__ bcount)
{
  __shared__ int hist[512];
  int t = threadIdx.x;
  for (int i = t; i < nbk; i += 256) hist[i] = 0;
  __syncthreads();
  long base = (long)blockIdx.x * 4096;
  #pragma unroll
  for (int k = 0; k < 16; ++k){
    long e = base + (long)k * 256 + t;
    if (e < E) atomicAdd(&hist[dst[e] >> shift], 1);
  }
  __syncthreads();
  for (int i = t; i < nbk; i += 256){
    int v = hist[i];
    if (v) atomicAdd(&bcount[i], v);
  }
}

// Single-block exclusive scan of bucket counts -> bucket start cursors.
__global__ __launch_bounds__(512) void bscan_kernel(
    const int* __restrict__ bcount, int nbk, int* __restrict__ gcur)
{
  __shared__ int sh[512];
  int t = threadIdx.x;
  int v = (t < nbk) ? bcount[t] : 0;
  sh[t] = v; __syncthreads();
  for (int off = 1; off < 512; off <<= 1){
    int x = (t >= off) ? sh[t - off] : 0;
    __syncthreads();
    sh[t] += x;
    __syncthreads();
  }
  if (t < nbk) gcur[t] = sh[t] - v;   // exclusive bucket start
}

// Bin edges by coarse dst-bucket (packed u32: src<<shift | local_dst).
// After this kernel, gcur[b] == END offset of bucket b's edge range.
__global__ __launch_bounds__(256) void bin_kernel(
    const int* __restrict__ src, const int* __restrict__ dst, int E, int shift, int nbk,
    int* __restrict__ gcur, unsigned* __restrict__ ebuf)
{
  __shared__ int hist[512];
  __shared__ int lbase[512];
  int t = threadIdx.x;
  int mask = (1 << shift) - 1;
  long base = (long)blockIdx.x * 4096;
  for (int i = t; i < nbk; i += 256) hist[i] = 0;
  __syncthreads();
  int s_[16], d_[16];
  #pragma unroll
  for (int k = 0; k < 16; ++k){
    long e = base + (long)k * 256 + t;
    if (e < E){
      s_[k] = src[e]; d_[k] = dst[e];
      atomicAdd(&hist[d_[k] >> shift], 1);
    } else d_[k] = -1;
  }
  __syncthreads();
  for (int i = t; i < nbk; i += 256){
    lbase[i] = atomicAdd(&gcur[i], hist[i]);
    hist[i] = 0;
  }
  __syncthreads();
  #pragma unroll
  for (int k = 0; k < 16; ++k){
    if (d_[k] >= 0){
      int b = d_[k] >> shift;
      int r = atomicAdd(&hist[b], 1);
      ebuf[lbase[b] + r] = ((unsigned)s_[k] << shift) | (unsigned)(d_[k] & mask);
    }
  }
}

// One workgroup OWNS one bucket: LDS per-node degree histogram -> block-local
// exclusive scan -> coalesced (start,deg) int2 writes -> LDS-cursor CSR placement.
__global__ __launch_bounds__(512) void fill_csr4_kernel(
    const unsigned* __restrict__ ebuf, const int* __restrict__ bend,
    int shift, int N, int2* __restrict__ sd, int* __restrict__ csr_src)
{
  __shared__ int cnt[4096];               // supports shift <= 12
  __shared__ int psum[512];
  int b = blockIdx.x;
  int t = threadIdx.x;
  int bsz = 1 << shift;
  int mask = bsz - 1;
  int nbase = b << shift;
  for (int i = t; i < bsz; i += 512) cnt[i] = 0;
  __syncthreads();
  int gs = (b == 0) ? 0 : bend[b - 1];
  int ge = bend[b];
  for (int e = gs + t; e < ge; e += 512)
    atomicAdd(&cnt[ebuf[e] & mask], 1);
  __syncthreads();
  // two-level exclusive scan over cnt[0..bsz)
  int k = bsz >> 9;                       // elems per thread (>=1)
  int base = t * k;
  int loc = 0;
  for (int j = 0; j < k; ++j) loc += cnt[base + j];
  psum[t] = loc;
  __syncthreads();
  for (int off = 1; off < 512; off <<= 1){
    int x = (t >= off) ? psum[t - off] : 0;
    __syncthreads();
    psum[t] += x;
    __syncthreads();
  }
  int run = gs + psum[t] - loc;           // global exclusive prefix for chunk
  for (int j = 0; j < k; ++j){
    int node = nbase + base + j;
    int c = cnt[base + j];
    cnt[base + j] = run;                  // becomes placement cursor
    if (node < N) sd[node] = make_int2(run, c);
    run += c;
  }
  __syncthreads();
  for (int e = gs + t; e < ge; e += 512){
    unsigned v = ebuf[e];
    int slot = atomicAdd(&cnt[v & mask], 1);
    csr_src[slot] = (int)(v >> shift);
  }
}

// f = h @ W (32x32) stored as FP16 (64B/row -> 1 line per edge gather),
// el stored as FP16x4 (8B/node, 1.6MB total -> L2-resident under fh stream),
// er per-head fp32. One thread per node.
// T = float (layer 0: emb rows) or __half (layer 1: fp16 h rows).
template <typename T>
__global__ __launch_bounds__(256) void fc_kernel(
    const T* __restrict__ hin, const int* __restrict__ nid,
    const float* __restrict__ W, const float* __restrict__ al, const float* __restrict__ ar,
    int n, __half* __restrict__ fh, __half* __restrict__ elh, float* __restrict__ er)
{
  __shared__ __align__(16) float Ws[1024];
  __shared__ float als[32], ars[32];
  int t = threadIdx.x;
  for (int i = t; i < 1024; i += 256) Ws[i] = W[i];
  if (t < 32){ als[t] = al[t]; ars[t] = ar[t]; }
  __syncthreads();
  int i = blockIdx.x * 256 + t;
  if (i >= n) return;
  long row = nid ? (long)nid[i] : (long)i;
  float h[32];
  if (sizeof(T) == 4){
    const float4* hp = (const float4*)((const float*)hin + row * 32);
    #pragma unroll
    for (int q = 0; q < 8; ++q){
      float4 v = hp[q];
      h[4*q+0] = v.x; h[4*q+1] = v.y; h[4*q+2] = v.z; h[4*q+3] = v.w;
    }
  } else {
    const uint2* hp = (const uint2*)((const __half*)hin + row * 32);
    #pragma unroll
    for (int q = 0; q < 8; ++q){
      uint2 raw = hp[q];
      float2 a = __half22float2(*(const __half2*)&raw.x);
      float2 b = __half22float2(*(const __half2*)&raw.y);
      h[4*q+0] = a.x; h[4*q+1] = a.y; h[4*q+2] = b.x; h[4*q+3] = b.y;
    }
  }
  float fv[32];
  #pragma unroll
  for (int j = 0; j < 32; j += 4){
    float ax = 0.f, ay = 0.f, az = 0.f, aw = 0.f;
    #pragma unroll
    for (int k = 0; k < 32; ++k){
      float hk = h[k];
      float4 w = *(const float4*)&Ws[k*32 + j];
      ax += hk * w.x; ay += hk * w.y; az += hk * w.z; aw += hk * w.w;
    }
    fv[j] = ax; fv[j+1] = ay; fv[j+2] = az; fv[j+3] = aw;
  }
  __half hrow[32];
  #pragma unroll
  for (int j = 0; j < 32; ++j) hrow[j] = __float2half_rn(fv[j]);
  float4* fp = (float4*)(fh + (size_t)i * 32);
  #pragma unroll
  for (int q = 0; q < 4; ++q) fp[q] = ((const float4*)hrow)[q];
  float elv[4], erv[4];
  #pragma unroll
  for (int hh = 0; hh < 4; ++hh){
    float a = 0.f, b = 0.f;
    #pragma unroll
    for (int d = 0; d < 8; ++d){
      a += fv[hh*8 + d] * als[hh*8 + d];
      b += fv[hh*8 + d] * ars[hh*8 + d];
    }
    elv[hh] = a; erv[hh] = b;
  }
  __half2 e01 = __halves2half2(__float2half_rn(elv[0]), __float2half_rn(elv[1]));
  __half2 e23 = __halves2half2(__float2half_rn(elv[2]), __float2half_rn(elv[3]));
  uint2 epk;
  epk.x = *(unsigned*)&e01;
  epk.y = *(unsigned*)&e23;
  *(uint2*)(elh + (size_t)i * 4) = epk;
  *(float4*)(er + (size_t)i * 4) = make_float4(erv[0], erv[1], erv[2], erv[3]);
}

// One wave per dst node, SINGLE-PASS fused softmax+gather.
// Deferred normalization: out = (sum_e x_e * f_e) / (sum_e x_e),
// x_e = exp(lrelu(el[u]+er[v])) computed lane-locally (8 lanes per edge,
// each owning a col-quad; 2B fp16 el load rides beside the 8B fh quad load).
// No LDS, no fence, one csr read; critical path sd -> csr -> {el || fh} -> FMA.
__global__ __launch_bounds__(256) void gat_agg_kernel(
    const int* __restrict__ csr_src, const int2* __restrict__ sd,
    const __half* __restrict__ fh, const __half* __restrict__ elh, const float* __restrict__ er,
    const float* __restrict__ bias, int n, __half* __restrict__ hout)
{
  int wid  = threadIdx.x >> 6;
  int lane = threadIdx.x & 63;
  int v = blockIdx.x * 4 + wid;
  if (v >= n) return;
  int2 sdv = sd[v];
  int s = sdv.x, d = sdv.y;
  int cq    = lane & 7;    // col-quad: cols 4cq..4cq+3
  int g     = lane >> 3;   // edge group 0..7
  int headq = cq >> 1;     // head of this col-quad
  float erh = er[(size_t)v * 4 + headq];

  float4 o4 = make_float4(0.f, 0.f, 0.f, 0.f);
  float dsum = 0.f;
  for (int base = 0; base < d; base += 64){
    int   u_r[8];
    float lv[8];
    uint2 raw[8];
    #pragma unroll
    for (int it = 0; it < 8; ++it){
      int i = base + g + it * 8;
      if (i < d) u_r[it] = csr_src[s + i];      // 8-lane broadcast
    }
    #pragma unroll
    for (int it = 0; it < 8; ++it){
      int i = base + g + it * 8;
      if (i < d){
        lv[it]  = __half2float(elh[(size_t)u_r[it] * 4 + headq]);       // 2B, L2-hot
        raw[it] = *(const uint2*)(fh + ((size_t)u_r[it] << 5) + (cq << 2)); // 8B of 64B row
      }
    }
    #pragma unroll
    for (int it = 0; it < 8; ++it){
      int i = base + g + it * 8;
      if (i < d){
        float x = __expf(lrelu(lv[it] + erh));
        dsum += x;
        float2 f01 = __half22float2(*(const __half2*)&raw[it].x);
        float2 f23 = __half22float2(*(const __half2*)&raw[it].y);
        o4.x = fmaf(x, f01.x, o4.x);
        o4.y = fmaf(x, f01.y, o4.y);
        o4.z = fmaf(x, f23.x, o4.z);
        o4.w = fmaf(x, f23.y, o4.w);
      }
    }
  }
  // reduce over the 8 edge-groups (cq preserved: offsets >= 8)
  #pragma unroll
  for (int off = 8; off < 64; off <<= 1){
    o4.x += __shfl_xor(o4.x, off);
    o4.y += __shfl_xor(o4.y, off);
    o4.z += __shfl_xor(o4.z, off);
    o4.w += __shfl_xor(o4.w, off);
    dsum += __shfl_xor(dsum, off);
  }
  if (lane < 8){
    float r = d > 0 ? 1.f / dsum : 0.f;
    float4 b4 = *(const float4*)(bias + cq * 4);
    __half2 h01 = __halves2half2(__float2half_rn(fmaxf(fmaf(o4.x, r, b4.x), 0.f)),
                                 __float2half_rn(fmaxf(fmaf(o4.y, r, b4.y), 0.f)));
    __half2 h23 = __halves2half2(__float2half_rn(fmaxf(fmaf(o4.z, r, b4.z), 0.f)),
                                 __float2half_rn(fmaxf(fmaf(o4.w, r, b4.w), 0.f)));
    uint2 pk;
    pk.x = *(unsigned*)&h01;
    pk.y = *(unsigned*)&h23;
    *(uint2*)(hout + (size_t)v * 32 + cq * 4) = pk;
  }
}

__device__ int lower_bound_dev(const int* a, int n, int key){
  int lo = 0, hi = n;
  while (lo < hi){
    int mid = (lo + hi) >> 1;
    if (a[mid] < key) lo = mid + 1; else hi = mid;
  }
  return lo;
}

// 8 slices per graph, atomic partial sums into hg (hg pre-zeroed). fp16 input.
__global__ void pool_kernel(const __half* __restrict__ hout, const int* __restrict__ gid,
                            int n, float* __restrict__ hg){
  __shared__ int lohi[2];
  int g  = blockIdx.x >> 3;
  int sl = blockIdx.x & 7;
  int t = threadIdx.x;
  if (t < 2) lohi[t] = lower_bound_dev(gid, n, g + t);
  __syncthreads();
  int lo = lohi[0], hi = lohi[1];
  int cnt = hi - lo;
  if (cnt <= 0) return;
  int chunk = (cnt + 7) >> 3;
  int rlo = lo + sl * chunk;
  int rhi = min(rlo + chunk, hi);
  if (rlo >= rhi) return;
  int col = t & 31, r0 = t >> 5;
  float acc = 0.f;
  for (int r = rlo + r0; r < rhi; r += 8)
    acc += __half2float(hout[(size_t)r * 32 + col]);
  __shared__ float red[256];
  red[t] = acc; __syncthreads();
  if (t < 128) red[t] += red[t + 128];
  __syncthreads();
  if (t < 64) red[t] += red[t + 64];
  __syncthreads();
  if (t < 32) atomicAdd(&hg[g * 32 + t], red[t] + red[t + 32]);
}

// Scorer MLP; folds the mean-pool divide (counts via binary search on gid).
__global__ void score_kernel(const float* __restrict__ hg, const int* __restrict__ gid, int n,
                             const float* __restrict__ sw1, const float* __restrict__ sb1,
                             const float* __restrict__ sw2, const float* __restrict__ sb2,
                             int B, float* __restrict__ out){
  int g = blockIdx.x * blockDim.x + threadIdx.x;
  if (g >= B) return;
  int lo = lower_bound_dev(gid, n, g);
  int hi = lower_bound_dev(gid, n, g + 1);
  float inv = 1.f / fmaxf((float)(hi - lo), 1.f);
  float hvec[32];
  const float4* hp = (const float4*)(hg + g * 32);
  #pragma unroll
  for (int q = 0; q < 8; ++q){
    float4 v = hp[q];
    hvec[4*q+0] = v.x * inv; hvec[4*q+1] = v.y * inv;
    hvec[4*q+2] = v.z * inv; hvec[4*q+3] = v.w * inv;
  }
  float o = sb2[0];
  #pragma unroll
  for (int j = 0; j < 32; ++j){
    float a = sb1[j];
    #pragma unroll
    for (int k = 0; k < 32; ++k) a += hvec[k] * sw1[k*32 + j];
    o += fmaxf(a, 0.f) * sw2[j];
  }
  out[g] = o;
}

extern "C" void kernel_launch(void* const* d_in, const int* in_sizes, int n_in,
                              void* d_out, int out_size, void* d_ws, size_t ws_size,
                              hipStream_t stream)
{
  const int*   node_ids = (const int*)d_in[0];
  const int*   srcp     = (const int*)d_in[1];
  const int*   dstp     = (const int*)d_in[2];
  const int*   gid      = (const int*)d_in[3];
  const float* emb      = (const float*)d_in[4];
  const float* W0       = (const float*)d_in[5];
  const float* al0      = (const float*)d_in[6];
  const float* ar0      = (const float*)d_in[7];
  const float* b0       = (const float*)d_in[8];
  const float* W1       = (const float*)d_in[9];
  const float* al1      = (const float*)d_in[10];
  const float* ar1      = (const float*)d_in[11];
  const float* b1       = (const float*)d_in[12];
  const float* sw1      = (const float*)d_in[13];
  const float* sb1      = (const float*)d_in[14];
  const float* sw2      = (const float*)d_in[15];
  const float* sb2      = (const float*)d_in[16];

  int N = in_sizes[0];
  int E = in_sizes[1];
  int B = out_size;           // output is [B,1] float32
  float* out = (float*)d_out;

  // Workspace carve-out (256B aligned)
  char* p = (char*)d_ws;
  auto alloc = [&](size_t bytes) -> char* {
    char* r = p;
    p += (bytes + 255) & ~(size_t)255;
    return r;
  };
  // Coarse dst-buckets: one workgroup per bucket in the fill pass.
  int shift = 9;
  while ((((long)N + (1L << shift) - 1) >> shift) > 512 && shift < 12) ++shift;
  int nbk = (int)(((long)N + (1L << shift) - 1) >> shift);

  int2*     sd      = (int2*)alloc((size_t)N * 8);
  int*      bcount  = (int*)alloc((size_t)nbk * 4);
  int*      gcur    = (int*)alloc((size_t)nbk * 4);
  int*      csr_src = (int*)alloc((size_t)E * 4);
  __half*   elh     = (__half*)alloc((size_t)N * 8);    // fp16x4 el rows (L2-resident)
  float*    er      = (float*)alloc((size_t)N * 16);
  size_t fbytes  = (size_t)N * 64;          // fp16 f rows
  size_t ebytes  = (size_t)E * 4;
  __half*   fh      = (__half*)alloc(fbytes > ebytes ? fbytes : ebytes);
  __half*   h       = (__half*)alloc((size_t)N * 64);   // fp16 h rows
  float*    hg      = (float*)alloc((size_t)B * 32 * 4);
  unsigned* ebuf    = (unsigned*)fh;  // disjoint lifetime: consumed before fc writes fh

  hipMemsetAsync(bcount, 0, (size_t)nbk * 4, stream);
  hipMemsetAsync(hg, 0, (size_t)B * 32 * 4, stream);

  int eb4k = (E + 4095) / 4096;
  bhist_kernel<<<eb4k, 256, 0, stream>>>(dstp, E, shift, nbk, bcount);
  bscan_kernel<<<1, 512, 0, stream>>>(bcount, nbk, gcur);
  bin_kernel<<<eb4k, 256, 0, stream>>>(srcp, dstp, E, shift, nbk, gcur, ebuf);
  // after bin: gcur[b] == end offset of bucket b
  fill_csr4_kernel<<<nbk, 512, 0, stream>>>(ebuf, gcur, shift, N, sd, csr_src);

  int nblk = (N + 255) / 256;
  int ablk = (N + 3) / 4;
  // Layer 0: h_in = emb[node_ids]
  fc_kernel<float><<<nblk, 256, 0, stream>>>(emb, node_ids, W0, al0, ar0, N, fh, elh, er);
  gat_agg_kernel<<<ablk, 256, 0, stream>>>(csr_src, sd, fh, elh, er, b0, N, h);
  // Layer 1: h_in = h (fp16)
  fc_kernel<__half><<<nblk, 256, 0, stream>>>(h, nullptr, W1, al1, ar1, N, fh, elh, er);
  gat_agg_kernel<<<ablk, 256, 0, stream>>>(csr_src, sd, fh, elh, er, b1, N, h);

  pool_kernel<<<B * 8, 256, 0, stream>>>(h, gid, N, hg);
  score_kernel<<<1, 64, 0, stream>>>(hg, gid, N, sw1, sb1, sw2, sb2, B, out);
}

// Round 13
// 307.671 us; speedup vs baseline: 1.9639x; 1.0856x over previous
//
#include <hip/hip_runtime.h>
#include <hip/hip_fp16.h>
#include <math.h>

__device__ __forceinline__ float lrelu(float x){ return x > 0.f ? x : 0.2f * x; }

// Bin edges by coarse dst-bucket into FIXED-CAPACITY regions (no pre-scan):
// packed u32 record src<<shift | local_dst; LDS histogram batches the global
// region-cursor atomics. gcur zero-initialized; after run gcur[b] = count.
__global__ __launch_bounds__(256) void bin_kernel(
    const int* __restrict__ src, const int* __restrict__ dst, int E, int shift, int nbk,
    int ECAP, int* __restrict__ gcur, unsigned* __restrict__ ebuf)
{
  __shared__ int hist[512];
  __shared__ int lbase[512];
  int t = threadIdx.x;
  int mask = (1 << shift) - 1;
  long base = (long)blockIdx.x * 4096;
  for (int i = t; i < nbk; i += 256) hist[i] = 0;
  __syncthreads();
  int s_[16], d_[16];
  #pragma unroll
  for (int k = 0; k < 16; ++k){
    long e = base + (long)k * 256 + t;
    if (e < E){
      s_[k] = src[e]; d_[k] = dst[e];
      atomicAdd(&hist[d_[k] >> shift], 1);
    } else d_[k] = -1;
  }
  __syncthreads();
  for (int i = t; i < nbk; i += 256){
    lbase[i] = atomicAdd(&gcur[i], hist[i]);
    hist[i] = 0;
  }
  __syncthreads();
  #pragma unroll
  for (int k = 0; k < 16; ++k){
    if (d_[k] >= 0){
      int b = d_[k] >> shift;
      int r = atomicAdd(&hist[b], 1);
      int slot = lbase[b] + r;
      if (slot < ECAP)   // 22-sigma insurance
        ebuf[(size_t)b * ECAP + slot] = ((unsigned)s_[k] << shift) | (unsigned)(d_[k] & mask);
    }
  }
}

// One workgroup OWNS one bucket: LDS per-node degree histogram -> local scan of
// PADDED degrees (round up to 4) -> (start,padded_deg) int2 + pad slots = dummy
// node N -> LDS-cursor placement. Bucket CSR region is fixed-capacity (CCAP),
// so buckets are fully independent (no cross-bucket scan needed).
__global__ __launch_bounds__(512) void fill_csr5_kernel(
    const unsigned* __restrict__ ebuf, const int* __restrict__ gcnt,
    int shift, int N, int ECAP, int CCAP,
    int2* __restrict__ sd, int* __restrict__ csr_src)
{
  __shared__ int cnt[4096];               // supports shift <= 12
  __shared__ int psum[512];
  int b = blockIdx.x;
  int t = threadIdx.x;
  int bsz = 1 << shift;
  int mask = bsz - 1;
  int nbase = b << shift;
  for (int i = t; i < bsz; i += 512) cnt[i] = 0;
  __syncthreads();
  int count = min(gcnt[b], ECAP);
  const unsigned* eb = ebuf + (size_t)b * ECAP;
  for (int e = t; e < count; e += 512)
    atomicAdd(&cnt[eb[e] & mask], 1);
  __syncthreads();
  // scan of padded degrees
  int k = bsz >> 9;                       // nodes per thread (>=1)
  int base = t * k;
  int loc = 0;
  for (int j = 0; j < k; ++j) loc += (cnt[base + j] + 3) & ~3;
  psum[t] = loc;
  __syncthreads();
  for (int off = 1; off < 512; off <<= 1){
    int x = (t >= off) ? psum[t - off] : 0;
    __syncthreads();
    psum[t] += x;
    __syncthreads();
  }
  int run = b * CCAP + psum[t] - loc;
  for (int j = 0; j < k; ++j){
    int node = nbase + base + j;
    int c  = cnt[base + j];
    int dp = (c + 3) & ~3;
    cnt[base + j] = run;                  // placement cursor
    if (node < N) sd[node] = make_int2(run, dp);
    for (int q = c; q < dp; ++q) csr_src[run + q] = N;  // pad -> dummy node
    run += dp;
  }
  __syncthreads();
  for (int e = t; e < count; e += 512){
    unsigned x = eb[e];
    int slot = atomicAdd(&cnt[x & mask], 1);
    csr_src[slot] = (int)(x >> shift);
  }
}

// f = h @ W (32x32) stored FP16 (64B/row), el stored FP16x4 (L2-resident),
// er per-head fp32. One thread per node; thread i==n writes the DUMMY row:
// fh row N = 0, elh[N] = -60000 (=> exp underflows to exactly 0 for pads).
// T = float (layer 0: emb rows) or __half (layer 1: fp16 h rows).
template <typename T>
__global__ __launch_bounds__(256) void fc_kernel(
    const T* __restrict__ hin, const int* __restrict__ nid,
    const float* __restrict__ W, const float* __restrict__ al, const float* __restrict__ ar,
    int n, __half* __restrict__ fh, __half* __restrict__ elh, float* __restrict__ er)
{
  __shared__ __align__(16) float Ws[1024];
  __shared__ float als[32], ars[32];
  int t = threadIdx.x;
  for (int i = t; i < 1024; i += 256) Ws[i] = W[i];
  if (t < 32){ als[t] = al[t]; ars[t] = ar[t]; }
  __syncthreads();
  int i = blockIdx.x * 256 + t;
  if (i > n) return;
  if (i == n){                    // dummy node for CSR padding
    float4 z = make_float4(0.f, 0.f, 0.f, 0.f);
    float4* fp = (float4*)(fh + (size_t)n * 32);
    #pragma unroll
    for (int q = 0; q < 4; ++q) fp[q] = z;
    __half2 e = __halves2half2(__float2half_rn(-60000.f), __float2half_rn(-60000.f));
    uint2 epk; epk.x = *(unsigned*)&e; epk.y = *(unsigned*)&e;
    *(uint2*)(elh + (size_t)n * 4) = epk;
    return;
  }
  long row = nid ? (long)nid[i] : (long)i;
  float h[32];
  if (sizeof(T) == 4){
    const float4* hp = (const float4*)((const float*)hin + row * 32);
    #pragma unroll
    for (int q = 0; q < 8; ++q){
      float4 v = hp[q];
      h[4*q+0] = v.x; h[4*q+1] = v.y; h[4*q+2] = v.z; h[4*q+3] = v.w;
    }
  } else {
    const uint2* hp = (const uint2*)((const __half*)hin + row * 32);
    #pragma unroll
    for (int q = 0; q < 8; ++q){
      uint2 raw = hp[q];
      float2 a = __half22float2(*(const __half2*)&raw.x);
      float2 b = __half22float2(*(const __half2*)&raw.y);
      h[4*q+0] = a.x; h[4*q+1] = a.y; h[4*q+2] = b.x; h[4*q+3] = b.y;
    }
  }
  float fv[32];
  #pragma unroll
  for (int j = 0; j < 32; j += 4){
    float ax = 0.f, ay = 0.f, az = 0.f, aw = 0.f;
    #pragma unroll
    for (int k = 0; k < 32; ++k){
      float hk = h[k];
      float4 w = *(const float4*)&Ws[k*32 + j];
      ax += hk * w.x; ay += hk * w.y; az += hk * w.z; aw += hk * w.w;
    }
    fv[j] = ax; fv[j+1] = ay; fv[j+2] = az; fv[j+3] = aw;
  }
  __half hrow[32];
  #pragma unroll
  for (int j = 0; j < 32; ++j) hrow[j] = __float2half_rn(fv[j]);
  float4* fp = (float4*)(fh + (size_t)i * 32);
  #pragma unroll
  for (int q = 0; q < 4; ++q) fp[q] = ((const float4*)hrow)[q];
  float elv[4], erv[4];
  #pragma unroll
  for (int hh = 0; hh < 4; ++hh){
    float a = 0.f, b = 0.f;
    #pragma unroll
    for (int d = 0; d < 8; ++d){
      a += fv[hh*8 + d] * als[hh*8 + d];
      b += fv[hh*8 + d] * ars[hh*8 + d];
    }
    elv[hh] = a; erv[hh] = b;
  }
  __half2 e01 = __halves2half2(__float2half_rn(elv[0]), __float2half_rn(elv[1]));
  __half2 e23 = __halves2half2(__float2half_rn(elv[2]), __float2half_rn(elv[3]));
  uint2 epk;
  epk.x = *(unsigned*)&e01;
  epk.y = *(unsigned*)&e23;
  *(uint2*)(elh + (size_t)i * 4) = epk;
  *(float4*)(er + (size_t)i * 4) = make_float4(erv[0], erv[1], erv[2], erv[3]);
}

// TWO nodes per wave (32 lanes each: 4 edge-groups x 8 col-lanes), single-pass
// fused softmax+gather with deferred normalization. Degrees padded to x4 with
// dummy edges (x=0) -> predicate-free inner loop, uniform for any degree.
// 32-bit indices -> SGPR-base + v-offset addressing.
__global__ __launch_bounds__(256) void gat_agg_kernel(
    const int* __restrict__ csr_src, const int2* __restrict__ sd,
    const __half* __restrict__ fh, const __half* __restrict__ elh, const float* __restrict__ er,
    const float* __restrict__ bias, int n, __half* __restrict__ hout)
{
  int wid  = threadIdx.x >> 6;
  int lane = threadIdx.x & 63;
  int hf   = lane >> 5;          // node slot within wave
  int l    = lane & 31;
  int cq   = l & 7;              // col-quad: cols 4cq..4cq+3
  int g    = l >> 3;             // edge-group 0..3
  int headq = cq >> 1;
  int v = blockIdx.x * 8 + wid * 2 + hf;
  bool valid = v < n;
  int vc = valid ? v : 0;
  int2 sdv = sd[vc];
  int s = sdv.x;
  int d = valid ? sdv.y : 0;     // padded degree (multiple of 4)
  float erh = er[(unsigned)vc * 4 + headq];

  float4 o4 = make_float4(0.f, 0.f, 0.f, 0.f);
  float dsum = 0.f;
  #pragma unroll 2
  for (int i = 0; i < d; i += 4){
    int u = csr_src[(unsigned)(s + i + g)];                       // 8-lane broadcast
    float lv = __half2float(elh[((unsigned)u << 2) + headq]);     // 2B, L2-hot
    uint2 raw = *(const uint2*)(fh + ((unsigned)u << 5) + (cq << 2)); // 8B of 64B row
    float x = __expf(lrelu(lv + erh));                            // pads: exactly 0
    dsum += x;
    float2 f01 = __half22float2(*(const __half2*)&raw.x);
    float2 f23 = __half22float2(*(const __half2*)&raw.y);
    o4.x = fmaf(x, f01.x, o4.x);
    o4.y = fmaf(x, f01.y, o4.y);
    o4.z = fmaf(x, f23.x, o4.z);
    o4.w = fmaf(x, f23.y, o4.w);
  }
  // reduce across the 4 edge-groups (stays within the 32-lane half)
  #pragma unroll
  for (int off = 8; off <= 16; off <<= 1){
    o4.x += __shfl_xor(o4.x, off);
    o4.y += __shfl_xor(o4.y, off);
    o4.z += __shfl_xor(o4.z, off);
    o4.w += __shfl_xor(o4.w, off);
    dsum += __shfl_xor(dsum, off);
  }
  if (l < 8 && valid){
    float r = dsum > 0.f ? 1.f / dsum : 0.f;
    float4 b4 = *(const float4*)(bias + cq * 4);
    __half2 h01 = __halves2half2(__float2half_rn(fmaxf(fmaf(o4.x, r, b4.x), 0.f)),
                                 __float2half_rn(fmaxf(fmaf(o4.y, r, b4.y), 0.f)));
    __half2 h23 = __halves2half2(__float2half_rn(fmaxf(fmaf(o4.z, r, b4.z), 0.f)),
                                 __float2half_rn(fmaxf(fmaf(o4.w, r, b4.w), 0.f)));
    uint2 pk;
    pk.x = *(unsigned*)&h01;
    pk.y = *(unsigned*)&h23;
    *(uint2*)(hout + (unsigned)v * 32 + cq * 4) = pk;
  }
}

__device__ int lower_bound_dev(const int* a, int n, int key){
  int lo = 0, hi = n;
  while (lo < hi){
    int mid = (lo + hi) >> 1;
    if (a[mid] < key) lo = mid + 1; else hi = mid;
  }
  return lo;
}

// 8 slices per graph, atomic partial sums into hg (hg pre-zeroed). fp16 input.
__global__ void pool_kernel(const __half* __restrict__ hout, const int* __restrict__ gid,
                            int n, float* __restrict__ hg){
  __shared__ int lohi[2];
  int g  = blockIdx.x >> 3;
  int sl = blockIdx.x & 7;
  int t = threadIdx.x;
  if (t < 2) lohi[t] = lower_bound_dev(gid, n, g + t);
  __syncthreads();
  int lo = lohi[0], hi = lohi[1];
  int cnt = hi - lo;
  if (cnt <= 0) return;
  int chunk = (cnt + 7) >> 3;
  int rlo = lo + sl * chunk;
  int rhi = min(rlo + chunk, hi);
  if (rlo >= rhi) return;
  int col = t & 31, r0 = t >> 5;
  float acc = 0.f;
  for (int r = rlo + r0; r < rhi; r += 8)
    acc += __half2float(hout[(size_t)r * 32 + col]);
  __shared__ float red[256];
  red[t] = acc; __syncthreads();
  if (t < 128) red[t] += red[t + 128];
  __syncthreads();
  if (t < 64) red[t] += red[t + 64];
  __syncthreads();
  if (t < 32) atomicAdd(&hg[g * 32 + t], red[t] + red[t + 32]);
}

// Scorer MLP; folds the mean-pool divide (counts via binary search on gid).
__global__ void score_kernel(const float* __restrict__ hg, const int* __restrict__ gid, int n,
                             const float* __restrict__ sw1, const float* __restrict__ sb1,
                             const float* __restrict__ sw2, const float* __restrict__ sb2,
                             int B, float* __restrict__ out){
  int g = blockIdx.x * blockDim.x + threadIdx.x;
  if (g >= B) return;
  int lo = lower_bound_dev(gid, n, g);
  int hi = lower_bound_dev(gid, n, g + 1);
  float inv = 1.f / fmaxf((float)(hi - lo), 1.f);
  float hvec[32];
  const float4* hp = (const float4*)(hg + g * 32);
  #pragma unroll
  for (int q = 0; q < 8; ++q){
    float4 v = hp[q];
    hvec[4*q+0] = v.x * inv; hvec[4*q+1] = v.y * inv;
    hvec[4*q+2] = v.z * inv; hvec[4*q+3] = v.w * inv;
  }
  float o = sb2[0];
  #pragma unroll
  for (int j = 0; j < 32; ++j){
    float a = sb1[j];
    #pragma unroll
    for (int k = 0; k < 32; ++k) a += hvec[k] * sw1[k*32 + j];
    o += fmaxf(a, 0.f) * sw2[j];
  }
  out[g] = o;
}

extern "C" void kernel_launch(void* const* d_in, const int* in_sizes, int n_in,
                              void* d_out, int out_size, void* d_ws, size_t ws_size,
                              hipStream_t stream)
{
  const int*   node_ids = (const int*)d_in[0];
  const int*   srcp     = (const int*)d_in[1];
  const int*   dstp     = (const int*)d_in[2];
  const int*   gid      = (const int*)d_in[3];
  const float* emb      = (const float*)d_in[4];
  const float* W0       = (const float*)d_in[5];
  const float* al0      = (const float*)d_in[6];
  const float* ar0      = (const float*)d_in[7];
  const float* b0       = (const float*)d_in[8];
  const float* W1       = (const float*)d_in[9];
  const float* al1      = (const float*)d_in[10];
  const float* ar1      = (const float*)d_in[11];
  const float* b1       = (const float*)d_in[12];
  const float* sw1      = (const float*)d_in[13];
  const float* sb1      = (const float*)d_in[14];
  const float* sw2      = (const float*)d_in[15];
  const float* sb2      = (const float*)d_in[16];

  int N = in_sizes[0];
  int E = in_sizes[1];
  int B = out_size;           // output is [B,1] float32
  float* out = (float*)d_out;

  // Workspace carve-out (256B aligned)
  char* p = (char*)d_ws;
  auto alloc = [&](size_t bytes) -> char* {
    char* r = p;
    p += (bytes + 255) & ~(size_t)255;
    return r;
  };
  // Coarse dst-buckets; one workgroup per bucket; fixed-capacity regions.
  int shift = 9;
  while ((((long)N + (1L << shift) - 1) >> shift) > 512 && shift < 12) ++shift;
  int nbk = (int)(((long)N + (1L << shift) - 1) >> shift);
  long mean = (long)E / nbk;
  int ECAP = (int)((mean + mean / 4 + 1024 + 255) & ~255L);   // ~22 sigma headroom
  int CCAP = (ECAP + 3 * (1 << shift) + 255) & ~255;          // hard pad bound

  int2*     sd      = (int2*)alloc((size_t)N * 8);
  int*      gcur    = (int*)alloc((size_t)nbk * 4);
  int*      csr_src = (int*)alloc((size_t)nbk * CCAP * 4);
  __half*   elh     = (__half*)alloc((size_t)(N + 1) * 8);    // fp16x4 el (+dummy)
  float*    er      = (float*)alloc((size_t)N * 16);
  size_t fbytes  = (size_t)(N + 1) * 64;                      // fp16 f rows (+dummy)
  size_t ebytes  = (size_t)nbk * ECAP * 4;
  __half*   fh      = (__half*)alloc(fbytes > ebytes ? fbytes : ebytes);
  __half*   h       = (__half*)alloc((size_t)N * 64);         // fp16 h rows
  float*    hg      = (float*)alloc((size_t)B * 32 * 4);
  unsigned* ebuf    = (unsigned*)fh;  // disjoint lifetime: consumed before fc writes fh

  hipMemsetAsync(gcur, 0, (size_t)nbk * 4, stream);
  hipMemsetAsync(hg, 0, (size_t)B * 32 * 4, stream);

  int eb4k = (E + 4095) / 4096;
  bin_kernel<<<eb4k, 256, 0, stream>>>(srcp, dstp, E, shift, nbk, ECAP, gcur, ebuf);
  fill_csr5_kernel<<<nbk, 512, 0, stream>>>(ebuf, gcur, shift, N, ECAP, CCAP, sd, csr_src);

  int nblk1 = (N + 1 + 255) / 256;   // +1: dummy row
  int ablk  = (N + 7) / 8;           // 2 nodes per wave, 4 waves per block
  // Layer 0: h_in = emb[node_ids]
  fc_kernel<float><<<nblk1, 256, 0, stream>>>(emb, node_ids, W0, al0, ar0, N, fh, elh, er);
  gat_agg_kernel<<<ablk, 256, 0, stream>>>(csr_src, sd, fh, elh, er, b0, N, h);
  // Layer 1: h_in = h (fp16)
  fc_kernel<__half><<<nblk1, 256, 0, stream>>>(h, nullptr, W1, al1, ar1, N, fh, elh, er);
  gat_agg_kernel<<<ablk, 256, 0, stream>>>(csr_src, sd, fh, elh, er, b1, N, h);

  pool_kernel<<<B * 8, 256, 0, stream>>>(h, gid, N, hg);
  score_kernel<<<1, 64, 0, stream>>>(hg, gid, N, sw1, sb1, sw2, sb2, B, out);
}

// Round 14
// 281.209 us; speedup vs baseline: 2.1488x; 1.0941x over previous
//
#include <hip/hip_runtime.h>
#include <hip/hip_fp16.h>
#include <math.h>

__device__ __forceinline__ float lrelu(float x){ return x > 0.f ? x : 0.2f * x; }

// Bin edges by coarse dst-bucket into FIXED-CAPACITY regions (no pre-scan):
// packed u32 record src<<shift | local_dst; LDS histogram batches the global
// region-cursor atomics. gcur zero-initialized; after run gcur[b] = count.
__global__ __launch_bounds__(256) void bin_kernel(
    const int* __restrict__ src, const int* __restrict__ dst, int E, int shift, int nbk,
    int ECAP, int* __restrict__ gcur, unsigned* __restrict__ ebuf)
{
  __shared__ int hist[512];
  __shared__ int lbase[512];
  int t = threadIdx.x;
  int mask = (1 << shift) - 1;
  long base = (long)blockIdx.x * 4096;
  for (int i = t; i < nbk; i += 256) hist[i] = 0;
  __syncthreads();
  int s_[16], d_[16];
  #pragma unroll
  for (int k = 0; k < 16; ++k){
    long e = base + (long)k * 256 + t;
    if (e < E){
      s_[k] = src[e]; d_[k] = dst[e];
      atomicAdd(&hist[d_[k] >> shift], 1);
    } else d_[k] = -1;
  }
  __syncthreads();
  for (int i = t; i < nbk; i += 256){
    lbase[i] = atomicAdd(&gcur[i], hist[i]);
    hist[i] = 0;
  }
  __syncthreads();
  #pragma unroll
  for (int k = 0; k < 16; ++k){
    if (d_[k] >= 0){
      int b = d_[k] >> shift;
      int r = atomicAdd(&hist[b], 1);
      int slot = lbase[b] + r;
      if (slot < ECAP)   // 22-sigma insurance
        ebuf[(size_t)b * ECAP + slot] = ((unsigned)s_[k] << shift) | (unsigned)(d_[k] & mask);
    }
  }
}

// One workgroup OWNS one bucket: LDS per-node degree histogram -> local scan of
// PADDED degrees (round up to 4) -> (start,padded_deg) int2 + pad slots = dummy
// node N -> LDS-cursor placement. Bucket CSR region is fixed-capacity (CCAP),
// so buckets are fully independent (no cross-bucket scan needed).
__global__ __launch_bounds__(512) void fill_csr5_kernel(
    const unsigned* __restrict__ ebuf, const int* __restrict__ gcnt,
    int shift, int N, int ECAP, int CCAP,
    int2* __restrict__ sd, int* __restrict__ csr_src)
{
  __shared__ int cnt[4096];               // supports shift <= 12
  __shared__ int psum[512];
  int b = blockIdx.x;
  int t = threadIdx.x;
  int bsz = 1 << shift;
  int mask = bsz - 1;
  int nbase = b << shift;
  for (int i = t; i < bsz; i += 512) cnt[i] = 0;
  __syncthreads();
  int count = min(gcnt[b], ECAP);
  const unsigned* eb = ebuf + (size_t)b * ECAP;
  for (int e = t; e < count; e += 512)
    atomicAdd(&cnt[eb[e] & mask], 1);
  __syncthreads();
  // scan of padded degrees
  int k = bsz >> 9;                       // nodes per thread (>=1)
  int base = t * k;
  int loc = 0;
  for (int j = 0; j < k; ++j) loc += (cnt[base + j] + 3) & ~3;
  psum[t] = loc;
  __syncthreads();
  for (int off = 1; off < 512; off <<= 1){
    int x = (t >= off) ? psum[t - off] : 0;
    __syncthreads();
    psum[t] += x;
    __syncthreads();
  }
  int run = b * CCAP + psum[t] - loc;
  for (int j = 0; j < k; ++j){
    int node = nbase + base + j;
    int c  = cnt[base + j];
    int dp = (c + 3) & ~3;
    cnt[base + j] = run;                  // placement cursor
    if (node < N) sd[node] = make_int2(run, dp);
    for (int q = c; q < dp; ++q) csr_src[run + q] = N;  // pad -> dummy node
    run += dp;
  }
  __syncthreads();
  for (int e = t; e < count; e += 512){
    unsigned x = eb[e];
    int slot = atomicAdd(&cnt[x & mask], 1);
    csr_src[slot] = (int)(x >> shift);
  }
}

// f = h @ W (32x32) stored FP16 (64B/row), el stored FP16x4 (L2-resident),
// er per-head fp32. One thread per node; thread i==n writes the DUMMY row:
// fh row N = 0, elh[N] = -60000 (=> exp underflows to exactly 0 for pads).
// T = float (layer 0: emb rows) or __half (layer 1: fp16 h rows).
template <typename T>
__global__ __launch_bounds__(256) void fc_kernel(
    const T* __restrict__ hin, const int* __restrict__ nid,
    const float* __restrict__ W, const float* __restrict__ al, const float* __restrict__ ar,
    int n, __half* __restrict__ fh, __half* __restrict__ elh, float* __restrict__ er)
{
  __shared__ __align__(16) float Ws[1024];
  __shared__ float als[32], ars[32];
  int t = threadIdx.x;
  for (int i = t; i < 1024; i += 256) Ws[i] = W[i];
  if (t < 32){ als[t] = al[t]; ars[t] = ar[t]; }
  __syncthreads();
  int i = blockIdx.x * 256 + t;
  if (i > n) return;
  if (i == n){                    // dummy node for CSR padding
    float4 z = make_float4(0.f, 0.f, 0.f, 0.f);
    float4* fp = (float4*)(fh + (size_t)n * 32);
    #pragma unroll
    for (int q = 0; q < 4; ++q) fp[q] = z;
    __half2 e = __halves2half2(__float2half_rn(-60000.f), __float2half_rn(-60000.f));
    uint2 epk; epk.x = *(unsigned*)&e; epk.y = *(unsigned*)&e;
    *(uint2*)(elh + (size_t)n * 4) = epk;
    return;
  }
  long row = nid ? (long)nid[i] : (long)i;
  float h[32];
  if (sizeof(T) == 4){
    const float4* hp = (const float4*)((const float*)hin + row * 32);
    #pragma unroll
    for (int q = 0; q < 8; ++q){
      float4 v = hp[q];
      h[4*q+0] = v.x; h[4*q+1] = v.y; h[4*q+2] = v.z; h[4*q+3] = v.w;
    }
  } else {
    const uint2* hp = (const uint2*)((const __half*)hin + row * 32);
    #pragma unroll
    for (int q = 0; q < 8; ++q){
      uint2 raw = hp[q];
      float2 a = __half22float2(*(const __half2*)&raw.x);
      float2 b = __half22float2(*(const __half2*)&raw.y);
      h[4*q+0] = a.x; h[4*q+1] = a.y; h[4*q+2] = b.x; h[4*q+3] = b.y;
    }
  }
  float fv[32];
  #pragma unroll
  for (int j = 0; j < 32; j += 4){
    float ax = 0.f, ay = 0.f, az = 0.f, aw = 0.f;
    #pragma unroll
    for (int k = 0; k < 32; ++k){
      float hk = h[k];
      float4 w = *(const float4*)&Ws[k*32 + j];
      ax += hk * w.x; ay += hk * w.y; az += hk * w.z; aw += hk * w.w;
    }
    fv[j] = ax; fv[j+1] = ay; fv[j+2] = az; fv[j+3] = aw;
  }
  __half hrow[32];
  #pragma unroll
  for (int j = 0; j < 32; ++j) hrow[j] = __float2half_rn(fv[j]);
  float4* fp = (float4*)(fh + (size_t)i * 32);
  #pragma unroll
  for (int q = 0; q < 4; ++q) fp[q] = ((const float4*)hrow)[q];
  float elv[4], erv[4];
  #pragma unroll
  for (int hh = 0; hh < 4; ++hh){
    float a = 0.f, b = 0.f;
    #pragma unroll
    for (int d = 0; d < 8; ++d){
      a += fv[hh*8 + d] * als[hh*8 + d];
      b += fv[hh*8 + d] * ars[hh*8 + d];
    }
    elv[hh] = a; erv[hh] = b;
  }
  __half2 e01 = __halves2half2(__float2half_rn(elv[0]), __float2half_rn(elv[1]));
  __half2 e23 = __halves2half2(__float2half_rn(elv[2]), __float2half_rn(elv[3]));
  uint2 epk;
  epk.x = *(unsigned*)&e01;
  epk.y = *(unsigned*)&e23;
  *(uint2*)(elh + (size_t)i * 4) = epk;
  *(float4*)(er + (size_t)i * 4) = make_float4(erv[0], erv[1], erv[2], erv[3]);
}

// TWO nodes per wave (32 lanes each: 4 edge-groups x 8 col-lanes), single-pass
// fused softmax+gather, 2-DEEP SOFTWARE PIPELINE: csr index prefetched 2 groups
// ahead, elh/fh data 1 group ahead (~6 loads in flight per node-slot). Tail
// prefetch indices clamp to the node's first edge (in-range, value unused).
// Degrees padded to x4 with dummy edges (x exactly 0) -> predicate-free math.
__global__ __launch_bounds__(256) void gat_agg_kernel(
    const int* __restrict__ csr_src, const int2* __restrict__ sd,
    const __half* __restrict__ fh, const __half* __restrict__ elh, const float* __restrict__ er,
    const float* __restrict__ bias, int n, __half* __restrict__ hout)
{
  int wid  = threadIdx.x >> 6;
  int lane = threadIdx.x & 63;
  int hf   = lane >> 5;          // node slot within wave
  int l    = lane & 31;
  int cq   = l & 7;              // col-quad: cols 4cq..4cq+3
  int g    = l >> 3;             // edge-group 0..3
  int headq = cq >> 1;
  int v = blockIdx.x * 8 + wid * 2 + hf;
  bool valid = v < n;
  int vc = valid ? v : 0;
  int2 sdv = sd[vc];
  int s = sdv.x;
  int d = valid ? sdv.y : 0;     // padded degree (multiple of 4)
  float erh = er[(unsigned)vc * 4 + headq];

  // pipeline prologue (clamped, min() guards d==0 unwritten-memory case)
  int a0 = (d > 0) ? s + g : 0;
  int a1 = (d > 4) ? s + 4 + g : a0;
  int u0 = min(csr_src[(unsigned)a0], n);
  int u1 = min(csr_src[(unsigned)a1], n);
  float lv0  = __half2float(elh[((unsigned)u0 << 2) + headq]);
  uint2 raw0 = *(const uint2*)(fh + ((unsigned)u0 << 5) + (cq << 2));

  float4 o4 = make_float4(0.f, 0.f, 0.f, 0.f);
  float dsum = 0.f;
  for (int i = 0; i < d; i += 4){
    int a2 = (i + 8 < d) ? s + i + 8 + g : a0;       // csr 2 groups ahead
    int u2 = csr_src[(unsigned)a2];
    float lv1  = __half2float(elh[((unsigned)u1 << 2) + headq]);   // data 1 ahead
    uint2 raw1 = *(const uint2*)(fh + ((unsigned)u1 << 5) + (cq << 2));
    float x = __expf(lrelu(lv0 + erh));              // pads: exactly 0
    dsum += x;
    float2 f01 = __half22float2(*(const __half2*)&raw0.x);
    float2 f23 = __half22float2(*(const __half2*)&raw0.y);
    o4.x = fmaf(x, f01.x, o4.x);
    o4.y = fmaf(x, f01.y, o4.y);
    o4.z = fmaf(x, f23.x, o4.z);
    o4.w = fmaf(x, f23.y, o4.w);
    u1 = u2; lv0 = lv1; raw0 = raw1;
  }
  // reduce across the 4 edge-groups (stays within the 32-lane half)
  #pragma unroll
  for (int off = 8; off <= 16; off <<= 1){
    o4.x += __shfl_xor(o4.x, off);
    o4.y += __shfl_xor(o4.y, off);
    o4.z += __shfl_xor(o4.z, off);
    o4.w += __shfl_xor(o4.w, off);
    dsum += __shfl_xor(dsum, off);
  }
  if (l < 8 && valid){
    float r = dsum > 0.f ? 1.f / dsum : 0.f;
    float4 b4 = *(const float4*)(bias + cq * 4);
    __half2 h01 = __halves2half2(__float2half_rn(fmaxf(fmaf(o4.x, r, b4.x), 0.f)),
                                 __float2half_rn(fmaxf(fmaf(o4.y, r, b4.y), 0.f)));
    __half2 h23 = __halves2half2(__float2half_rn(fmaxf(fmaf(o4.z, r, b4.z), 0.f)),
                                 __float2half_rn(fmaxf(fmaf(o4.w, r, b4.w), 0.f)));
    uint2 pk;
    pk.x = *(unsigned*)&h01;
    pk.y = *(unsigned*)&h23;
    *(uint2*)(hout + (unsigned)v * 32 + cq * 4) = pk;
  }
}

__device__ int lower_bound_dev(const int* a, int n, int key){
  int lo = 0, hi = n;
  while (lo < hi){
    int mid = (lo + hi) >> 1;
    if (a[mid] < key) lo = mid + 1; else hi = mid;
  }
  return lo;
}

// 8 slices per graph, partial sums to DISTINCT slots (no atomics, no memset;
// every slice always writes -> no stale data across replays). fp16 input.
__global__ void pool_kernel(const __half* __restrict__ hout, const int* __restrict__ gid,
                            int n, float* __restrict__ hg8){
  __shared__ int lohi[2];
  int g  = blockIdx.x >> 3;
  int sl = blockIdx.x & 7;
  int t = threadIdx.x;
  if (t < 2) lohi[t] = lower_bound_dev(gid, n, g + t);
  __syncthreads();
  int lo = lohi[0], hi = lohi[1];
  int cnt = hi - lo;
  int chunk = (cnt + 7) >> 3;
  int rlo = lo + sl * chunk;
  int rhi = min(rlo + chunk, hi);
  int col = t & 31, r0 = t >> 5;
  float acc = 0.f;
  for (int r = rlo + r0; r < rhi; r += 8)
    acc += __half2float(hout[(size_t)r * 32 + col]);
  __shared__ float red[256];
  red[t] = acc; __syncthreads();
  if (t < 128) red[t] += red[t + 128];
  __syncthreads();
  if (t < 64) red[t] += red[t + 64];
  __syncthreads();
  if (t < 32) hg8[((size_t)g * 8 + sl) * 32 + t] = red[t] + red[t + 32];
}

// Scorer MLP; sums the 8 pool slices and folds the mean-pool divide.
__global__ void score_kernel(const float* __restrict__ hg8, const int* __restrict__ gid, int n,
                             const float* __restrict__ sw1, const float* __restrict__ sb1,
                             const float* __restrict__ sw2, const float* __restrict__ sb2,
                             int B, float* __restrict__ out){
  int g = blockIdx.x * blockDim.x + threadIdx.x;
  if (g >= B) return;
  int lo = lower_bound_dev(gid, n, g);
  int hi = lower_bound_dev(gid, n, g + 1);
  float inv = 1.f / fmaxf((float)(hi - lo), 1.f);
  float hvec[32];
  #pragma unroll
  for (int k = 0; k < 32; ++k) hvec[k] = 0.f;
  for (int sl = 0; sl < 8; ++sl){
    const float4* hp = (const float4*)(hg8 + ((size_t)g * 8 + sl) * 32);
    #pragma unroll
    for (int q = 0; q < 8; ++q){
      float4 vv = hp[q];
      hvec[4*q+0] += vv.x; hvec[4*q+1] += vv.y;
      hvec[4*q+2] += vv.z; hvec[4*q+3] += vv.w;
    }
  }
  #pragma unroll
  for (int k = 0; k < 32; ++k) hvec[k] *= inv;
  float o = sb2[0];
  #pragma unroll
  for (int j = 0; j < 32; ++j){
    float a = sb1[j];
    #pragma unroll
    for (int k = 0; k < 32; ++k) a += hvec[k] * sw1[k*32 + j];
    o += fmaxf(a, 0.f) * sw2[j];
  }
  out[g] = o;
}

extern "C" void kernel_launch(void* const* d_in, const int* in_sizes, int n_in,
                              void* d_out, int out_size, void* d_ws, size_t ws_size,
                              hipStream_t stream)
{
  const int*   node_ids = (const int*)d_in[0];
  const int*   srcp     = (const int*)d_in[1];
  const int*   dstp     = (const int*)d_in[2];
  const int*   gid      = (const int*)d_in[3];
  const float* emb      = (const float*)d_in[4];
  const float* W0       = (const float*)d_in[5];
  const float* al0      = (const float*)d_in[6];
  const float* ar0      = (const float*)d_in[7];
  const float* b0       = (const float*)d_in[8];
  const float* W1       = (const float*)d_in[9];
  const float* al1      = (const float*)d_in[10];
  const float* ar1      = (const float*)d_in[11];
  const float* b1       = (const float*)d_in[12];
  const float* sw1      = (const float*)d_in[13];
  const float* sb1      = (const float*)d_in[14];
  const float* sw2      = (const float*)d_in[15];
  const float* sb2      = (const float*)d_in[16];

  int N = in_sizes[0];
  int E = in_sizes[1];
  int B = out_size;           // output is [B,1] float32
  float* out = (float*)d_out;

  // Workspace carve-out (256B aligned)
  char* p = (char*)d_ws;
  auto alloc = [&](size_t bytes) -> char* {
    char* r = p;
    p += (bytes + 255) & ~(size_t)255;
    return r;
  };
  // Coarse dst-buckets; one workgroup per bucket; fixed-capacity regions.
  int shift = 9;
  while ((((long)N + (1L << shift) - 1) >> shift) > 512 && shift < 12) ++shift;
  int nbk = (int)(((long)N + (1L << shift) - 1) >> shift);
  long mean = (long)E / nbk;
  int ECAP = (int)((mean + mean / 4 + 1024 + 255) & ~255L);   // ~22 sigma headroom
  int CCAP = (ECAP + 3 * (1 << shift) + 255) & ~255;          // hard pad bound

  int2*     sd      = (int2*)alloc((size_t)N * 8);
  int*      gcur    = (int*)alloc((size_t)nbk * 4);
  int*      csr_src = (int*)alloc((size_t)nbk * CCAP * 4);
  __half*   elh     = (__half*)alloc((size_t)(N + 1) * 8);    // fp16x4 el (+dummy)
  float*    er      = (float*)alloc((size_t)N * 16);
  size_t fbytes  = (size_t)(N + 1) * 64;                      // fp16 f rows (+dummy)
  size_t ebytes  = (size_t)nbk * ECAP * 4;
  __half*   fh      = (__half*)alloc(fbytes > ebytes ? fbytes : ebytes);
  __half*   h       = (__half*)alloc((size_t)N * 64);         // fp16 h rows
  float*    hg8     = (float*)alloc((size_t)B * 8 * 32 * 4);
  unsigned* ebuf    = (unsigned*)fh;  // disjoint lifetime: consumed before fc writes fh

  hipMemsetAsync(gcur, 0, (size_t)nbk * 4, stream);

  int eb4k = (E + 4095) / 4096;
  bin_kernel<<<eb4k, 256, 0, stream>>>(srcp, dstp, E, shift, nbk, ECAP, gcur, ebuf);
  fill_csr5_kernel<<<nbk, 512, 0, stream>>>(ebuf, gcur, shift, N, ECAP, CCAP, sd, csr_src);

  int nblk1 = (N + 1 + 255) / 256;   // +1: dummy row
  int ablk  = (N + 7) / 8;           // 2 nodes per wave, 4 waves per block
  // Layer 0: h_in = emb[node_ids]
  fc_kernel<float><<<nblk1, 256, 0, stream>>>(emb, node_ids, W0, al0, ar0, N, fh, elh, er);
  gat_agg_kernel<<<ablk, 256, 0, stream>>>(csr_src, sd, fh, elh, er, b0, N, h);
  // Layer 1: h_in = h (fp16)
  fc_kernel<__half><<<nblk1, 256, 0, stream>>>(h, nullptr, W1, al1, ar1, N, fh, elh, er);
  gat_agg_kernel<<<ablk, 256, 0, stream>>>(csr_src, sd, fh, elh, er, b1, N, h);

  pool_kernel<<<B * 8, 256, 0, stream>>>(h, gid, N, hg8);
  score_kernel<<<1, 64, 0, stream>>>(hg8, gid, N, sw1, sb1, sw2, sb2, B, out);
}

// Round 15
// 279.990 us; speedup vs baseline: 2.1581x; 1.0044x over previous
//
#include <hip/hip_runtime.h>
#include <hip/hip_fp16.h>
#include <math.h>

__device__ __forceinline__ float lrelu(float x){ return x > 0.f ? x : 0.2f * x; }

// Zero the bucket cursors (replaces hipMemsetAsync: rocclr fillBuffer showed a
// pathological ~75us dispatch for tiny fills inside the captured graph).
__global__ void zero_kernel(int* __restrict__ p, int n){
  int i = threadIdx.x;
  if (i < n) p[i] = 0;
}

// Bin edges by coarse dst-bucket into FIXED-CAPACITY regions (no pre-scan):
// packed u32 record src<<shift | local_dst; LDS histogram batches the global
// region-cursor atomics. gcur zero-initialized; after run gcur[b] = count.
__global__ __launch_bounds__(256) void bin_kernel(
    const int* __restrict__ src, const int* __restrict__ dst, int E, int shift, int nbk,
    int ECAP, int* __restrict__ gcur, unsigned* __restrict__ ebuf)
{
  __shared__ int hist[512];
  __shared__ int lbase[512];
  int t = threadIdx.x;
  int mask = (1 << shift) - 1;
  long base = (long)blockIdx.x * 4096;
  for (int i = t; i < nbk; i += 256) hist[i] = 0;
  __syncthreads();
  int s_[16], d_[16];
  #pragma unroll
  for (int k = 0; k < 16; ++k){
    long e = base + (long)k * 256 + t;
    if (e < E){
      s_[k] = src[e]; d_[k] = dst[e];
      atomicAdd(&hist[d_[k] >> shift], 1);
    } else d_[k] = -1;
  }
  __syncthreads();
  for (int i = t; i < nbk; i += 256){
    lbase[i] = atomicAdd(&gcur[i], hist[i]);
    hist[i] = 0;
  }
  __syncthreads();
  #pragma unroll
  for (int k = 0; k < 16; ++k){
    if (d_[k] >= 0){
      int b = d_[k] >> shift;
      int r = atomicAdd(&hist[b], 1);
      int slot = lbase[b] + r;
      if (slot < ECAP)   // 22-sigma insurance
        ebuf[(size_t)b * ECAP + slot] = ((unsigned)s_[k] << shift) | (unsigned)(d_[k] & mask);
    }
  }
}

// One workgroup OWNS one bucket: LDS per-node degree histogram -> local scan of
// PADDED degrees (round up to 4) -> (start,padded_deg) int2 + pad slots = dummy
// node N -> LDS-cursor placement. Bucket CSR region is fixed-capacity (CCAP),
// so buckets are fully independent (no cross-bucket scan needed).
__global__ __launch_bounds__(512) void fill_csr5_kernel(
    const unsigned* __restrict__ ebuf, const int* __restrict__ gcnt,
    int shift, int N, int ECAP, int CCAP,
    int2* __restrict__ sd, int* __restrict__ csr_src)
{
  __shared__ int cnt[4096];               // supports shift <= 12
  __shared__ int psum[512];
  int b = blockIdx.x;
  int t = threadIdx.x;
  int bsz = 1 << shift;
  int mask = bsz - 1;
  int nbase = b << shift;
  for (int i = t; i < bsz; i += 512) cnt[i] = 0;
  __syncthreads();
  int count = min(gcnt[b], ECAP);
  const unsigned* eb = ebuf + (size_t)b * ECAP;
  for (int e = t; e < count; e += 512)
    atomicAdd(&cnt[eb[e] & mask], 1);
  __syncthreads();
  // scan of padded degrees
  int k = bsz >> 9;                       // nodes per thread (>=1)
  int base = t * k;
  int loc = 0;
  for (int j = 0; j < k; ++j) loc += (cnt[base + j] + 3) & ~3;
  psum[t] = loc;
  __syncthreads();
  for (int off = 1; off < 512; off <<= 1){
    int x = (t >= off) ? psum[t - off] : 0;
    __syncthreads();
    psum[t] += x;
    __syncthreads();
  }
  int run = b * CCAP + psum[t] - loc;
  for (int j = 0; j < k; ++j){
    int node = nbase + base + j;
    int c  = cnt[base + j];
    int dp = (c + 3) & ~3;
    cnt[base + j] = run;                  // placement cursor
    if (node < N) sd[node] = make_int2(run, dp);
    for (int q = c; q < dp; ++q) csr_src[run + q] = N;  // pad -> dummy node
    run += dp;
  }
  __syncthreads();
  for (int e = t; e < count; e += 512){
    unsigned x = eb[e];
    int slot = atomicAdd(&cnt[x & mask], 1);
    csr_src[slot] = (int)(x >> shift);
  }
}

// f = h @ W (32x32) stored FP16 (64B/row), el stored FP16x4 (L2-resident),
// er per-head fp32. One thread per node; thread i==n writes the DUMMY row:
// fh row N = 0, elh[N] = -60000 (=> exp underflows to exactly 0 for pads).
// T = float (layer 0: emb rows) or __half (layer 1: fp16 h rows).
template <typename T>
__global__ __launch_bounds__(256) void fc_kernel(
    const T* __restrict__ hin, const int* __restrict__ nid,
    const float* __restrict__ W, const float* __restrict__ al, const float* __restrict__ ar,
    int n, __half* __restrict__ fh, __half* __restrict__ elh, float* __restrict__ er)
{
  __shared__ __align__(16) float Ws[1024];
  __shared__ float als[32], ars[32];
  int t = threadIdx.x;
  for (int i = t; i < 1024; i += 256) Ws[i] = W[i];
  if (t < 32){ als[t] = al[t]; ars[t] = ar[t]; }
  __syncthreads();
  int i = blockIdx.x * 256 + t;
  if (i > n) return;
  if (i == n){                    // dummy node for CSR padding
    float4 z = make_float4(0.f, 0.f, 0.f, 0.f);
    float4* fp = (float4*)(fh + (size_t)n * 32);
    #pragma unroll
    for (int q = 0; q < 4; ++q) fp[q] = z;
    __half2 e = __halves2half2(__float2half_rn(-60000.f), __float2half_rn(-60000.f));
    uint2 epk; epk.x = *(unsigned*)&e; epk.y = *(unsigned*)&e;
    *(uint2*)(elh + (size_t)n * 4) = epk;
    return;
  }
  long row = nid ? (long)nid[i] : (long)i;
  float h[32];
  if (sizeof(T) == 4){
    const float4* hp = (const float4*)((const float*)hin + row * 32);
    #pragma unroll
    for (int q = 0; q < 8; ++q){
      float4 v = hp[q];
      h[4*q+0] = v.x; h[4*q+1] = v.y; h[4*q+2] = v.z; h[4*q+3] = v.w;
    }
  } else {
    const uint2* hp = (const uint2*)((const __half*)hin + row * 32);
    #pragma unroll
    for (int q = 0; q < 8; ++q){
      uint2 raw = hp[q];
      float2 a = __half22float2(*(const __half2*)&raw.x);
      float2 b = __half22float2(*(const __half2*)&raw.y);
      h[4*q+0] = a.x; h[4*q+1] = a.y; h[4*q+2] = b.x; h[4*q+3] = b.y;
    }
  }
  float fv[32];
  #pragma unroll
  for (int j = 0; j < 32; j += 4){
    float ax = 0.f, ay = 0.f, az = 0.f, aw = 0.f;
    #pragma unroll
    for (int k = 0; k < 32; ++k){
      float hk = h[k];
      float4 w = *(const float4*)&Ws[k*32 + j];
      ax += hk * w.x; ay += hk * w.y; az += hk * w.z; aw += hk * w.w;
    }
    fv[j] = ax; fv[j+1] = ay; fv[j+2] = az; fv[j+3] = aw;
  }
  __half hrow[32];
  #pragma unroll
  for (int j = 0; j < 32; ++j) hrow[j] = __float2half_rn(fv[j]);
  float4* fp = (float4*)(fh + (size_t)i * 32);
  #pragma unroll
  for (int q = 0; q < 4; ++q) fp[q] = ((const float4*)hrow)[q];
  float elv[4], erv[4];
  #pragma unroll
  for (int hh = 0; hh < 4; ++hh){
    float a = 0.f, b = 0.f;
    #pragma unroll
    for (int d = 0; d < 8; ++d){
      a += fv[hh*8 + d] * als[hh*8 + d];
      b += fv[hh*8 + d] * ars[hh*8 + d];
    }
    elv[hh] = a; erv[hh] = b;
  }
  __half2 e01 = __halves2half2(__float2half_rn(elv[0]), __float2half_rn(elv[1]));
  __half2 e23 = __halves2half2(__float2half_rn(elv[2]), __float2half_rn(elv[3]));
  uint2 epk;
  epk.x = *(unsigned*)&e01;
  epk.y = *(unsigned*)&e23;
  *(uint2*)(elh + (size_t)i * 4) = epk;
  *(float4*)(er + (size_t)i * 4) = make_float4(erv[0], erv[1], erv[2], erv[3]);
}

// TWO nodes per wave (32 lanes each: 4 edge-groups x 8 col-lanes), single-pass
// fused softmax+gather, 2-DEEP SOFTWARE PIPELINE: csr index prefetched 2 groups
// ahead, elh/fh data 1 group ahead (~6 loads in flight per node-slot). Tail
// prefetch indices clamp to the node's first edge (in-range, value unused).
// Degrees padded to x4 with dummy edges (x exactly 0) -> predicate-free math.
__global__ __launch_bounds__(256) void gat_agg_kernel(
    const int* __restrict__ csr_src, const int2* __restrict__ sd,
    const __half* __restrict__ fh, const __half* __restrict__ elh, const float* __restrict__ er,
    const float* __restrict__ bias, int n, __half* __restrict__ hout)
{
  int wid  = threadIdx.x >> 6;
  int lane = threadIdx.x & 63;
  int hf   = lane >> 5;          // node slot within wave
  int l    = lane & 31;
  int cq   = l & 7;              // col-quad: cols 4cq..4cq+3
  int g    = l >> 3;             // edge-group 0..3
  int headq = cq >> 1;
  int v = blockIdx.x * 8 + wid * 2 + hf;
  bool valid = v < n;
  int vc = valid ? v : 0;
  int2 sdv = sd[vc];
  int s = sdv.x;
  int d = valid ? sdv.y : 0;     // padded degree (multiple of 4)
  float erh = er[(unsigned)vc * 4 + headq];

  // pipeline prologue (clamped, min() guards d==0 unwritten-memory case)
  int a0 = (d > 0) ? s + g : 0;
  int a1 = (d > 4) ? s + 4 + g : a0;
  int u0 = min(csr_src[(unsigned)a0], n);
  int u1 = min(csr_src[(unsigned)a1], n);
  float lv0  = __half2float(elh[((unsigned)u0 << 2) + headq]);
  uint2 raw0 = *(const uint2*)(fh + ((unsigned)u0 << 5) + (cq << 2));

  float4 o4 = make_float4(0.f, 0.f, 0.f, 0.f);
  float dsum = 0.f;
  for (int i = 0; i < d; i += 4){
    int a2 = (i + 8 < d) ? s + i + 8 + g : a0;       // csr 2 groups ahead
    int u2 = csr_src[(unsigned)a2];
    float lv1  = __half2float(elh[((unsigned)u1 << 2) + headq]);   // data 1 ahead
    uint2 raw1 = *(const uint2*)(fh + ((unsigned)u1 << 5) + (cq << 2));
    float x = __expf(lrelu(lv0 + erh));              // pads: exactly 0
    dsum += x;
    float2 f01 = __half22float2(*(const __half2*)&raw0.x);
    float2 f23 = __half22float2(*(const __half2*)&raw0.y);
    o4.x = fmaf(x, f01.x, o4.x);
    o4.y = fmaf(x, f01.y, o4.y);
    o4.z = fmaf(x, f23.x, o4.z);
    o4.w = fmaf(x, f23.y, o4.w);
    u1 = u2; lv0 = lv1; raw0 = raw1;
  }
  // reduce across the 4 edge-groups (stays within the 32-lane half)
  #pragma unroll
  for (int off = 8; off <= 16; off <<= 1){
    o4.x += __shfl_xor(o4.x, off);
    o4.y += __shfl_xor(o4.y, off);
    o4.z += __shfl_xor(o4.z, off);
    o4.w += __shfl_xor(o4.w, off);
    dsum += __shfl_xor(dsum, off);
  }
  if (l < 8 && valid){
    float r = dsum > 0.f ? 1.f / dsum : 0.f;
    float4 b4 = *(const float4*)(bias + cq * 4);
    __half2 h01 = __halves2half2(__float2half_rn(fmaxf(fmaf(o4.x, r, b4.x), 0.f)),
                                 __float2half_rn(fmaxf(fmaf(o4.y, r, b4.y), 0.f)));
    __half2 h23 = __halves2half2(__float2half_rn(fmaxf(fmaf(o4.z, r, b4.z), 0.f)),
                                 __float2half_rn(fmaxf(fmaf(o4.w, r, b4.w), 0.f)));
    uint2 pk;
    pk.x = *(unsigned*)&h01;
    pk.y = *(unsigned*)&h23;
    *(uint2*)(hout + (unsigned)v * 32 + cq * 4) = pk;
  }
}

__device__ int lower_bound_dev(const int* a, int n, int key){
  int lo = 0, hi = n;
  while (lo < hi){
    int mid = (lo + hi) >> 1;
    if (a[mid] < key) lo = mid + 1; else hi = mid;
  }
  return lo;
}

// 8 slices per graph, partial sums to DISTINCT slots (no atomics, no memset;
// every slice always writes -> no stale data across replays). fp16 input.
__global__ void pool_kernel(const __half* __restrict__ hout, const int* __restrict__ gid,
                            int n, float* __restrict__ hg8){
  __shared__ int lohi[2];
  int g  = blockIdx.x >> 3;
  int sl = blockIdx.x & 7;
  int t = threadIdx.x;
  if (t < 2) lohi[t] = lower_bound_dev(gid, n, g + t);
  __syncthreads();
  int lo = lohi[0], hi = lohi[1];
  int cnt = hi - lo;
  int chunk = (cnt + 7) >> 3;
  int rlo = lo + sl * chunk;
  int rhi = min(rlo + chunk, hi);
  int col = t & 31, r0 = t >> 5;
  float acc = 0.f;
  for (int r = rlo + r0; r < rhi; r += 8)
    acc += __half2float(hout[(size_t)r * 32 + col]);
  __shared__ float red[256];
  red[t] = acc; __syncthreads();
  if (t < 128) red[t] += red[t + 128];
  __syncthreads();
  if (t < 64) red[t] += red[t + 64];
  __syncthreads();
  if (t < 32) hg8[((size_t)g * 8 + sl) * 32 + t] = red[t] + red[t + 32];
}

// Scorer MLP; sums the 8 pool slices and folds the mean-pool divide.
__global__ void score_kernel(const float* __restrict__ hg8, const int* __restrict__ gid, int n,
                             const float* __restrict__ sw1, const float* __restrict__ sb1,
                             const float* __restrict__ sw2, const float* __restrict__ sb2,
                             int B, float* __restrict__ out){
  int g = blockIdx.x * blockDim.x + threadIdx.x;
  if (g >= B) return;
  int lo = lower_bound_dev(gid, n, g);
  int hi = lower_bound_dev(gid, n, g + 1);
  float inv = 1.f / fmaxf((float)(hi - lo), 1.f);
  float hvec[32];
  #pragma unroll
  for (int k = 0; k < 32; ++k) hvec[k] = 0.f;
  for (int sl = 0; sl < 8; ++sl){
    const float4* hp = (const float4*)(hg8 + ((size_t)g * 8 + sl) * 32);
    #pragma unroll
    for (int q = 0; q < 8; ++q){
      float4 vv = hp[q];
      hvec[4*q+0] += vv.x; hvec[4*q+1] += vv.y;
      hvec[4*q+2] += vv.z; hvec[4*q+3] += vv.w;
    }
  }
  #pragma unroll
  for (int k = 0; k < 32; ++k) hvec[k] *= inv;
  float o = sb2[0];
  #pragma unroll
  for (int j = 0; j < 32; ++j){
    float a = sb1[j];
    #pragma unroll
    for (int k = 0; k < 32; ++k) a += hvec[k] * sw1[k*32 + j];
    o += fmaxf(a, 0.f) * sw2[j];
  }
  out[g] = o;
}

extern "C" void kernel_launch(void* const* d_in, const int* in_sizes, int n_in,
                              void* d_out, int out_size, void* d_ws, size_t ws_size,
                              hipStream_t stream)
{
  const int*   node_ids = (const int*)d_in[0];
  const int*   srcp     = (const int*)d_in[1];
  const int*   dstp     = (const int*)d_in[2];
  const int*   gid      = (const int*)d_in[3];
  const float* emb      = (const float*)d_in[4];
  const float* W0       = (const float*)d_in[5];
  const float* al0      = (const float*)d_in[6];
  const float* ar0      = (const float*)d_in[7];
  const float* b0       = (const float*)d_in[8];
  const float* W1       = (const float*)d_in[9];
  const float* al1      = (const float*)d_in[10];
  const float* ar1      = (const float*)d_in[11];
  const float* b1       = (const float*)d_in[12];
  const float* sw1      = (const float*)d_in[13];
  const float* sb1      = (const float*)d_in[14];
  const float* sw2      = (const float*)d_in[15];
  const float* sb2      = (const float*)d_in[16];

  int N = in_sizes[0];
  int E = in_sizes[1];
  int B = out_size;           // output is [B,1] float32
  float* out = (float*)d_out;

  // Workspace carve-out (256B aligned)
  char* p = (char*)d_ws;
  auto alloc = [&](size_t bytes) -> char* {
    char* r = p;
    p += (bytes + 255) & ~(size_t)255;
    return r;
  };
  // Coarse dst-buckets; one workgroup per bucket; fixed-capacity regions.
  int shift = 9;
  while ((((long)N + (1L << shift) - 1) >> shift) > 512 && shift < 12) ++shift;
  int nbk = (int)(((long)N + (1L << shift) - 1) >> shift);
  long mean = (long)E / nbk;
  int ECAP = (int)((mean + mean / 4 + 1024 + 255) & ~255L);   // ~22 sigma headroom
  int CCAP = (ECAP + 3 * (1 << shift) + 255) & ~255;          // hard pad bound

  int2*     sd      = (int2*)alloc((size_t)N * 8);
  int*      gcur    = (int*)alloc((size_t)nbk * 4);
  int*      csr_src = (int*)alloc((size_t)nbk * CCAP * 4);
  __half*   elh     = (__half*)alloc((size_t)(N + 1) * 8);    // fp16x4 el (+dummy)
  float*    er      = (float*)alloc((size_t)N * 16);
  size_t fbytes  = (size_t)(N + 1) * 64;                      // fp16 f rows (+dummy)
  size_t ebytes  = (size_t)nbk * ECAP * 4;
  __half*   fh      = (__half*)alloc(fbytes > ebytes ? fbytes : ebytes);
  __half*   h       = (__half*)alloc((size_t)N * 64);         // fp16 h rows
  float*    hg8     = (float*)alloc((size_t)B * 8 * 32 * 4);
  unsigned* ebuf    = (unsigned*)fh;  // disjoint lifetime: consumed before fc writes fh

  zero_kernel<<<1, 512, 0, stream>>>(gcur, nbk);

  int eb4k = (E + 4095) / 4096;
  bin_kernel<<<eb4k, 256, 0, stream>>>(srcp, dstp, E, shift, nbk, ECAP, gcur, ebuf);
  fill_csr5_kernel<<<nbk, 512, 0, stream>>>(ebuf, gcur, shift, N, ECAP, CCAP, sd, csr_src);

  int nblk1 = (N + 1 + 255) / 256;   // +1: dummy row
  int ablk  = (N + 7) / 8;           // 2 nodes per wave, 4 waves per block
  // Layer 0: h_in = emb[node_ids]
  fc_kernel<float><<<nblk1, 256, 0, stream>>>(emb, node_ids, W0, al0, ar0, N, fh, elh, er);
  gat_agg_kernel<<<ablk, 256, 0, stream>>>(csr_src, sd, fh, elh, er, b0, N, h);
  // Layer 1: h_in = h (fp16)
  fc_kernel<__half><<<nblk1, 256, 0, stream>>>(h, nullptr, W1, al1, ar1, N, fh, elh, er);
  gat_agg_kernel<<<ablk, 256, 0, stream>>>(csr_src, sd, fh, elh, er, b1, N, h);

  pool_kernel<<<B * 8, 256, 0, stream>>>(h, gid, N, hg8);
  score_kernel<<<1, 64, 0, stream>>>(hg8, gid, N, sw1, sb1, sw2, sb2, B, out);
}

// Round 16
// 279.895 us; speedup vs baseline: 2.1588x; 1.0003x over previous
//
#include <hip/hip_runtime.h>
#include <hip/hip_fp16.h>
#include <math.h>

__device__ __forceinline__ float lrelu(float x){ return x > 0.f ? x : 0.2f * x; }

// Zero the bucket cursors (tiny in-graph fill; ~2us single block).
__global__ void zero_kernel(int* __restrict__ p, int n){
  int i = threadIdx.x;
  if (i < n) p[i] = 0;
}

// Bin edges by coarse dst-bucket into FIXED-CAPACITY regions (no pre-scan):
// packed u32 record src<<shift | local_dst; LDS histogram batches the global
// region-cursor atomics. gcur zero-initialized; after run gcur[b] = count.
__global__ __launch_bounds__(256) void bin_kernel(
    const int* __restrict__ src, const int* __restrict__ dst, int E, int shift, int nbk,
    int ECAP, int* __restrict__ gcur, unsigned* __restrict__ ebuf)
{
  __shared__ int hist[512];
  __shared__ int lbase[512];
  int t = threadIdx.x;
  int mask = (1 << shift) - 1;
  long base = (long)blockIdx.x * 4096;
  for (int i = t; i < nbk; i += 256) hist[i] = 0;
  __syncthreads();
  int s_[16], d_[16];
  #pragma unroll
  for (int k = 0; k < 16; ++k){
    long e = base + (long)k * 256 + t;
    if (e < E){
      s_[k] = src[e]; d_[k] = dst[e];
      atomicAdd(&hist[d_[k] >> shift], 1);
    } else d_[k] = -1;
  }
  __syncthreads();
  for (int i = t; i < nbk; i += 256){
    lbase[i] = atomicAdd(&gcur[i], hist[i]);
    hist[i] = 0;
  }
  __syncthreads();
  #pragma unroll
  for (int k = 0; k < 16; ++k){
    if (d_[k] >= 0){
      int b = d_[k] >> shift;
      int r = atomicAdd(&hist[b], 1);
      int slot = lbase[b] + r;
      if (slot < ECAP)   // 22-sigma insurance
        ebuf[(size_t)b * ECAP + slot] = ((unsigned)s_[k] << shift) | (unsigned)(d_[k] & mask);
    }
  }
}

// One workgroup OWNS one bucket: LDS per-node degree histogram -> local scan of
// PADDED degrees (round up to 4) -> (start,padded_deg) int2 + pad slots = dummy
// node N -> LDS-cursor placement. Bucket CSR region is fixed-capacity (CCAP),
// so buckets are fully independent (no cross-bucket scan needed).
__global__ __launch_bounds__(512) void fill_csr5_kernel(
    const unsigned* __restrict__ ebuf, const int* __restrict__ gcnt,
    int shift, int N, int ECAP, int CCAP,
    int2* __restrict__ sd, int* __restrict__ csr_src)
{
  __shared__ int cnt[4096];               // supports shift <= 12
  __shared__ int psum[512];
  int b = blockIdx.x;
  int t = threadIdx.x;
  int bsz = 1 << shift;
  int mask = bsz - 1;
  int nbase = b << shift;
  for (int i = t; i < bsz; i += 512) cnt[i] = 0;
  __syncthreads();
  int count = min(gcnt[b], ECAP);
  const unsigned* eb = ebuf + (size_t)b * ECAP;
  for (int e = t; e < count; e += 512)
    atomicAdd(&cnt[eb[e] & mask], 1);
  __syncthreads();
  // scan of padded degrees
  int k = bsz >> 9;                       // nodes per thread (>=1)
  int base = t * k;
  int loc = 0;
  for (int j = 0; j < k; ++j) loc += (cnt[base + j] + 3) & ~3;
  psum[t] = loc;
  __syncthreads();
  for (int off = 1; off < 512; off <<= 1){
    int x = (t >= off) ? psum[t - off] : 0;
    __syncthreads();
    psum[t] += x;
    __syncthreads();
  }
  int run = b * CCAP + psum[t] - loc;
  for (int j = 0; j < k; ++j){
    int node = nbase + base + j;
    int c  = cnt[base + j];
    int dp = (c + 3) & ~3;
    cnt[base + j] = run;                  // placement cursor
    if (node < N) sd[node] = make_int2(run, dp);
    for (int q = c; q < dp; ++q) csr_src[run + q] = N;  // pad -> dummy node
    run += dp;
  }
  __syncthreads();
  for (int e = t; e < count; e += 512){
    unsigned x = eb[e];
    int slot = atomicAdd(&cnt[x & mask], 1);
    csr_src[slot] = (int)(x >> shift);
  }
}

// f = h @ W (32x32) stored FP16 (64B/row), el stored FP16x4 (L2-resident),
// er per-head fp32. One thread per node; thread i==n writes the DUMMY row:
// fh row N = 0, elh[N] = -60000 (=> exp underflows to exactly 0 for pads).
// T = float (layer 0: emb rows) or __half (layer 1: fp16 h rows).
template <typename T>
__global__ __launch_bounds__(256) void fc_kernel(
    const T* __restrict__ hin, const int* __restrict__ nid,
    const float* __restrict__ W, const float* __restrict__ al, const float* __restrict__ ar,
    int n, __half* __restrict__ fh, __half* __restrict__ elh, float* __restrict__ er)
{
  __shared__ __align__(16) float Ws[1024];
  __shared__ float als[32], ars[32];
  int t = threadIdx.x;
  for (int i = t; i < 1024; i += 256) Ws[i] = W[i];
  if (t < 32){ als[t] = al[t]; ars[t] = ar[t]; }
  __syncthreads();
  int i = blockIdx.x * 256 + t;
  if (i > n) return;
  if (i == n){                    // dummy node for CSR padding
    float4 z = make_float4(0.f, 0.f, 0.f, 0.f);
    float4* fp = (float4*)(fh + (size_t)n * 32);
    #pragma unroll
    for (int q = 0; q < 4; ++q) fp[q] = z;
    __half2 e = __halves2half2(__float2half_rn(-60000.f), __float2half_rn(-60000.f));
    uint2 epk; epk.x = *(unsigned*)&e; epk.y = *(unsigned*)&e;
    *(uint2*)(elh + (size_t)n * 4) = epk;
    return;
  }
  long row = nid ? (long)nid[i] : (long)i;
  float h[32];
  if (sizeof(T) == 4){
    const float4* hp = (const float4*)((const float*)hin + row * 32);
    #pragma unroll
    for (int q = 0; q < 8; ++q){
      float4 v = hp[q];
      h[4*q+0] = v.x; h[4*q+1] = v.y; h[4*q+2] = v.z; h[4*q+3] = v.w;
    }
  } else {
    const uint2* hp = (const uint2*)((const __half*)hin + row * 32);
    #pragma unroll
    for (int q = 0; q < 8; ++q){
      uint2 raw = hp[q];
      float2 a = __half22float2(*(const __half2*)&raw.x);
      float2 b = __half22float2(*(const __half2*)&raw.y);
      h[4*q+0] = a.x; h[4*q+1] = a.y; h[4*q+2] = b.x; h[4*q+3] = b.y;
    }
  }
  float fv[32];
  #pragma unroll
  for (int j = 0; j < 32; j += 4){
    float ax = 0.f, ay = 0.f, az = 0.f, aw = 0.f;
    #pragma unroll
    for (int k = 0; k < 32; ++k){
      float hk = h[k];
      float4 w = *(const float4*)&Ws[k*32 + j];
      ax += hk * w.x; ay += hk * w.y; az += hk * w.z; aw += hk * w.w;
    }
    fv[j] = ax; fv[j+1] = ay; fv[j+2] = az; fv[j+3] = aw;
  }
  __half hrow[32];
  #pragma unroll
  for (int j = 0; j < 32; ++j) hrow[j] = __float2half_rn(fv[j]);
  float4* fp = (float4*)(fh + (size_t)i * 32);
  #pragma unroll
  for (int q = 0; q < 4; ++q) fp[q] = ((const float4*)hrow)[q];
  float elv[4], erv[4];
  #pragma unroll
  for (int hh = 0; hh < 4; ++hh){
    float a = 0.f, b = 0.f;
    #pragma unroll
    for (int d = 0; d < 8; ++d){
      a += fv[hh*8 + d] * als[hh*8 + d];
      b += fv[hh*8 + d] * ars[hh*8 + d];
    }
    elv[hh] = a; erv[hh] = b;
  }
  __half2 e01 = __halves2half2(__float2half_rn(elv[0]), __float2half_rn(elv[1]));
  __half2 e23 = __halves2half2(__float2half_rn(elv[2]), __float2half_rn(elv[3]));
  uint2 epk;
  epk.x = *(unsigned*)&e01;
  epk.y = *(unsigned*)&e23;
  *(uint2*)(elh + (size_t)i * 4) = epk;
  *(float4*)(er + (size_t)i * 4) = make_float4(erv[0], erv[1], erv[2], erv[3]);
}

// TWO nodes per wave (32 lanes each: 4 edge-groups x 8 col-lanes), single-pass
// fused softmax+gather, 3-DEEP SOFTWARE PIPELINE: csr index prefetched 3 groups
// ahead, elh/fh data 2 groups ahead (~9 loads in flight per node-slot) to cover
// L2-miss->L3 latency. Tail prefetch indices clamp to the node's first edge
// (in-range within this node's written, x4-padded region; value unused).
// Degrees padded to x4 with dummy edges (x exactly 0) -> predicate-free math.
__global__ __launch_bounds__(256) void gat_agg_kernel(
    const int* __restrict__ csr_src, const int2* __restrict__ sd,
    const __half* __restrict__ fh, const __half* __restrict__ elh, const float* __restrict__ er,
    const float* __restrict__ bias, int n, __half* __restrict__ hout)
{
  int wid  = threadIdx.x >> 6;
  int lane = threadIdx.x & 63;
  int hf   = lane >> 5;          // node slot within wave
  int l    = lane & 31;
  int cq   = l & 7;              // col-quad: cols 4cq..4cq+3
  int g    = l >> 3;             // edge-group 0..3
  int headq = cq >> 1;
  int v = blockIdx.x * 8 + wid * 2 + hf;
  bool valid = v < n;
  int vc = valid ? v : 0;
  int2 sdv = sd[vc];
  int s = sdv.x;
  int d = valid ? sdv.y : 0;     // padded degree (multiple of 4)
  float erh = er[(unsigned)vc * 4 + headq];

  // pipeline prologue (clamped; min() guards d==0 unwritten-memory case)
  int a0 = (d > 0) ? s + g : 0;
  int a1 = (d > 4) ? s + 4 + g : a0;
  int a2 = (d > 8) ? s + 8 + g : a0;
  int u0 = min(csr_src[(unsigned)a0], n);
  int u1 = min(csr_src[(unsigned)a1], n);
  int u2 = min(csr_src[(unsigned)a2], n);
  float lv0  = __half2float(elh[((unsigned)u0 << 2) + headq]);
  uint2 raw0 = *(const uint2*)(fh + ((unsigned)u0 << 5) + (cq << 2));
  float lv1  = __half2float(elh[((unsigned)u1 << 2) + headq]);
  uint2 raw1 = *(const uint2*)(fh + ((unsigned)u1 << 5) + (cq << 2));

  float4 o4 = make_float4(0.f, 0.f, 0.f, 0.f);
  float dsum = 0.f;
  for (int i = 0; i < d; i += 4){
    int a3 = (i + 12 < d) ? s + i + 12 + g : a0;     // csr 3 groups ahead
    int u3 = csr_src[(unsigned)a3];
    float lv2  = __half2float(elh[((unsigned)u2 << 2) + headq]);   // data 2 ahead
    uint2 raw2 = *(const uint2*)(fh + ((unsigned)u2 << 5) + (cq << 2));
    float x = __expf(lrelu(lv0 + erh));              // pads: exactly 0
    dsum += x;
    float2 f01 = __half22float2(*(const __half2*)&raw0.x);
    float2 f23 = __half22float2(*(const __half2*)&raw0.y);
    o4.x = fmaf(x, f01.x, o4.x);
    o4.y = fmaf(x, f01.y, o4.y);
    o4.z = fmaf(x, f23.x, o4.z);
    o4.w = fmaf(x, f23.y, o4.w);
    u2 = u3;
    lv0 = lv1; raw0 = raw1;
    lv1 = lv2; raw1 = raw2;
  }
  // reduce across the 4 edge-groups (stays within the 32-lane half)
  #pragma unroll
  for (int off = 8; off <= 16; off <<= 1){
    o4.x += __shfl_xor(o4.x, off);
    o4.y += __shfl_xor(o4.y, off);
    o4.z += __shfl_xor(o4.z, off);
    o4.w += __shfl_xor(o4.w, off);
    dsum += __shfl_xor(dsum, off);
  }
  if (l < 8 && valid){
    float r = dsum > 0.f ? 1.f / dsum : 0.f;
    float4 b4 = *(const float4*)(bias + cq * 4);
    __half2 h01 = __halves2half2(__float2half_rn(fmaxf(fmaf(o4.x, r, b4.x), 0.f)),
                                 __float2half_rn(fmaxf(fmaf(o4.y, r, b4.y), 0.f)));
    __half2 h23 = __halves2half2(__float2half_rn(fmaxf(fmaf(o4.z, r, b4.z), 0.f)),
                                 __float2half_rn(fmaxf(fmaf(o4.w, r, b4.w), 0.f)));
    uint2 pk;
    pk.x = *(unsigned*)&h01;
    pk.y = *(unsigned*)&h23;
    *(uint2*)(hout + (unsigned)v * 32 + cq * 4) = pk;
  }
}

__device__ int lower_bound_dev(const int* a, int n, int key){
  int lo = 0, hi = n;
  while (lo < hi){
    int mid = (lo + hi) >> 1;
    if (a[mid] < key) lo = mid + 1; else hi = mid;
  }
  return lo;
}

// 8 slices per graph, partial sums to DISTINCT slots (no atomics, no memset;
// every slice always writes -> no stale data across replays). fp16 input.
__global__ void pool_kernel(const __half* __restrict__ hout, const int* __restrict__ gid,
                            int n, float* __restrict__ hg8){
  __shared__ int lohi[2];
  int g  = blockIdx.x >> 3;
  int sl = blockIdx.x & 7;
  int t = threadIdx.x;
  if (t < 2) lohi[t] = lower_bound_dev(gid, n, g + t);
  __syncthreads();
  int lo = lohi[0], hi = lohi[1];
  int cnt = hi - lo;
  int chunk = (cnt + 7) >> 3;
  int rlo = lo + sl * chunk;
  int rhi = min(rlo + chunk, hi);
  int col = t & 31, r0 = t >> 5;
  float acc = 0.f;
  for (int r = rlo + r0; r < rhi; r += 8)
    acc += __half2float(hout[(size_t)r * 32 + col]);
  __shared__ float red[256];
  red[t] = acc; __syncthreads();
  if (t < 128) red[t] += red[t + 128];
  __syncthreads();
  if (t < 64) red[t] += red[t + 64];
  __syncthreads();
  if (t < 32) hg8[((size_t)g * 8 + sl) * 32 + t] = red[t] + red[t + 32];
}

// Scorer MLP; sums the 8 pool slices and folds the mean-pool divide.
__global__ void score_kernel(const float* __restrict__ hg8, const int* __restrict__ gid, int n,
                             const float* __restrict__ sw1, const float* __restrict__ sb1,
                             const float* __restrict__ sw2, const float* __restrict__ sb2,
                             int B, float* __restrict__ out){
  int g = blockIdx.x * blockDim.x + threadIdx.x;
  if (g >= B) return;
  int lo = lower_bound_dev(gid, n, g);
  int hi = lower_bound_dev(gid, n, g + 1);
  float inv = 1.f / fmaxf((float)(hi - lo), 1.f);
  float hvec[32];
  #pragma unroll
  for (int k = 0; k < 32; ++k) hvec[k] = 0.f;
  for (int sl = 0; sl < 8; ++sl){
    const float4* hp = (const float4*)(hg8 + ((size_t)g * 8 + sl) * 32);
    #pragma unroll
    for (int q = 0; q < 8; ++q){
      float4 vv = hp[q];
      hvec[4*q+0] += vv.x; hvec[4*q+1] += vv.y;
      hvec[4*q+2] += vv.z; hvec[4*q+3] += vv.w;
    }
  }
  #pragma unroll
  for (int k = 0; k < 32; ++k) hvec[k] *= inv;
  float o = sb2[0];
  #pragma unroll
  for (int j = 0; j < 32; ++j){
    float a = sb1[j];
    #pragma unroll
    for (int k = 0; k < 32; ++k) a += hvec[k] * sw1[k*32 + j];
    o += fmaxf(a, 0.f) * sw2[j];
  }
  out[g] = o;
}

extern "C" void kernel_launch(void* const* d_in, const int* in_sizes, int n_in,
                              void* d_out, int out_size, void* d_ws, size_t ws_size,
                              hipStream_t stream)
{
  const int*   node_ids = (const int*)d_in[0];
  const int*   srcp     = (const int*)d_in[1];
  const int*   dstp     = (const int*)d_in[2];
  const int*   gid      = (const int*)d_in[3];
  const float* emb      = (const float*)d_in[4];
  const float* W0       = (const float*)d_in[5];
  const float* al0      = (const float*)d_in[6];
  const float* ar0      = (const float*)d_in[7];
  const float* b0       = (const float*)d_in[8];
  const float* W1       = (const float*)d_in[9];
  const float* al1      = (const float*)d_in[10];
  const float* ar1      = (const float*)d_in[11];
  const float* b1       = (const float*)d_in[12];
  const float* sw1      = (const float*)d_in[13];
  const float* sb1      = (const float*)d_in[14];
  const float* sw2      = (const float*)d_in[15];
  const float* sb2      = (const float*)d_in[16];

  int N = in_sizes[0];
  int E = in_sizes[1];
  int B = out_size;           // output is [B,1] float32
  float* out = (float*)d_out;

  // Workspace carve-out (256B aligned)
  char* p = (char*)d_ws;
  auto alloc = [&](size_t bytes) -> char* {
    char* r = p;
    p += (bytes + 255) & ~(size_t)255;
    return r;
  };
  // Coarse dst-buckets; one workgroup per bucket; fixed-capacity regions.
  int shift = 9;
  while ((((long)N + (1L << shift) - 1) >> shift) > 512 && shift < 12) ++shift;
  int nbk = (int)(((long)N + (1L << shift) - 1) >> shift);
  long mean = (long)E / nbk;
  int ECAP = (int)((mean + mean / 4 + 1024 + 255) & ~255L);   // ~22 sigma headroom
  int CCAP = (ECAP + 3 * (1 << shift) + 255) & ~255;          // hard pad bound

  int2*     sd      = (int2*)alloc((size_t)N * 8);
  int*      gcur    = (int*)alloc((size_t)nbk * 4);
  int*      csr_src = (int*)alloc((size_t)nbk * CCAP * 4);
  __half*   elh     = (__half*)alloc((size_t)(N + 1) * 8);    // fp16x4 el (+dummy)
  float*    er      = (float*)alloc((size_t)N * 16);
  size_t fbytes  = (size_t)(N + 1) * 64;                      // fp16 f rows (+dummy)
  size_t ebytes  = (size_t)nbk * ECAP * 4;
  __half*   fh      = (__half*)alloc(fbytes > ebytes ? fbytes : ebytes);
  __half*   h       = (__half*)alloc((size_t)N * 64);         // fp16 h rows
  float*    hg8     = (float*)alloc((size_t)B * 8 * 32 * 4);
  unsigned* ebuf    = (unsigned*)fh;  // disjoint lifetime: consumed before fc writes fh

  zero_kernel<<<1, 512, 0, stream>>>(gcur, nbk);

  int eb4k = (E + 4095) / 4096;
  bin_kernel<<<eb4k, 256, 0, stream>>>(srcp, dstp, E, shift, nbk, ECAP, gcur, ebuf);
  fill_csr5_kernel<<<nbk, 512, 0, stream>>>(ebuf, gcur, shift, N, ECAP, CCAP, sd, csr_src);

  int nblk1 = (N + 1 + 255) / 256;   // +1: dummy row
  int ablk  = (N + 7) / 8;           // 2 nodes per wave, 4 waves per block
  // Layer 0: h_in = emb[node_ids]
  fc_kernel<float><<<nblk1, 256, 0, stream>>>(emb, node_ids, W0, al0, ar0, N, fh, elh, er);
  gat_agg_kernel<<<ablk, 256, 0, stream>>>(csr_src, sd, fh, elh, er, b0, N, h);
  // Layer 1: h_in = h (fp16)
  fc_kernel<__half><<<nblk1, 256, 0, stream>>>(h, nullptr, W1, al1, ar1, N, fh, elh, er);
  gat_agg_kernel<<<ablk, 256, 0, stream>>>(csr_src, sd, fh, elh, er, b1, N, h);

  pool_kernel<<<B * 8, 256, 0, stream>>>(h, gid, N, hg8);
  score_kernel<<<1, 64, 0, stream>>>(hg8, gid, N, sw1, sb1, sw2, sb2, B, out);
}